// Round 2
// baseline (590.896 us; speedup 1.0000x reference)
//
#include <hip/hip_runtime.h>
#include <math.h>

// Problem constants (from setup_inputs): H=300, D=600, B=256 graphs,
// Nu=Nv=8192 nodes, batch arrays SORTED (enables block-diagonal mask).
#define HDIM 300
#define DDIM 600
#define NGR  256

typedef float vf4 __attribute__((ext_vector_type(4)));  // native vec for nontemporal builtin

__device__ __forceinline__ float wred_sum(float v){
  #pragma unroll
  for(int o=32;o;o>>=1) v += __shfl_xor(v,o,64);
  return v;
}
__device__ __forceinline__ float wred_max(float v){
  #pragma unroll
  for(int o=32;o;o>>=1) v = fmaxf(v,__shfl_xor(v,o,64));
  return v;
}
__device__ __forceinline__ float sigm(float x){ return 1.f/(1.f+expf(-x)); }

// ---------------- K1: row l2-normalize (one wave per node) ----------------
__global__ __launch_bounds__(256) void k_norm(const float* __restrict__ xu,
    const float* __restrict__ xv, float* __restrict__ su, float* __restrict__ sv,
    int Nu, int Nv){
  int wid = (blockIdx.x * 256 + threadIdx.x) >> 6;
  int lane = threadIdx.x & 63;
  if (wid >= Nu + Nv) return;
  const float* src; float* dst;
  if (wid < Nu){ src = xu + (size_t)wid*HDIM; dst = su + (size_t)wid*HDIM; }
  else         { src = xv + (size_t)(wid-Nu)*HDIM; dst = sv + (size_t)(wid-Nu)*HDIM; }
  float v[5]; float s = 0.f;
  #pragma unroll
  for(int c=0;c<5;c++){ int k = lane + 64*c; float x = (k<HDIM)? src[k] : 0.f; v[c]=x; s += x*x; }
  s = wred_sum(s);
  float inv = 1.f / fmaxf(sqrtf(s), 1e-12f);
  #pragma unroll
  for(int c=0;c<5;c++){ int k = lane + 64*c; if (k<HDIM) dst[k] = v[c]*inv; }
}

// ---- K2: graph offsets (binary search, sorted batch) + step-1 LSTM state ----
// Step 1 of set2set: q_star=h=c=0 -> gates = b_ih + b_hh (input independent).
__global__ __launch_bounds__(640) void k_off_h1(const int* __restrict__ ub,
    const int* __restrict__ vb, int Nu, int Nv, int* __restrict__ uoff,
    int* __restrict__ voff, const float* __restrict__ b_ih,
    const float* __restrict__ b_hh, float* __restrict__ h1, float* __restrict__ c1){
  int t = threadIdx.x;
  if (t < NGR){
    int lo=0, hi=Nu;
    while(lo<hi){ int mid=(lo+hi)>>1; if (ub[mid] < t) lo=mid+1; else hi=mid; }
    uoff[t]=lo; if (t==0) uoff[NGR]=Nu;
  } else if (t < 2*NGR){
    int g=t-NGR; int lo=0, hi=Nv;
    while(lo<hi){ int mid=(lo+hi)>>1; if (vb[mid] < g) lo=mid+1; else hi=mid; }
    voff[g]=lo; if (g==0) voff[NGR]=Nv;
  }
  if (t < DDIM){
    float gi = b_ih[t]        + b_hh[t];
    float gg = b_ih[1200+t]   + b_hh[1200+t];
    float go = b_ih[1800+t]   + b_hh[1800+t];
    float c  = sigm(gi)*tanhf(gg);         // f-gate * c0 = 0
    c1[t]=c; h1[t]=sigm(go)*tanhf(c);
  }
}

// ---- K3/K4: per-row kernel. WRITE_MAP=true (solute rows): zero-fill the
// 8192-wide map row (nontemporal), compute in-graph dots (the map block),
// accumulate prime = sum_j m_ij * other_row_j, and e1 = [row,prime]·q1.
// WRITE_MAP=false (solvent rows): same minus the map writes (dots recomputed;
// cheaper than re-reading scattered map from HBM).
template<bool WRITE_MAP>
__global__ __launch_bounds__(256) void k_prime(const float* __restrict__ xa,
    const float* __restrict__ xb, const int* __restrict__ mybatch,
    const int* __restrict__ ooff, float* __restrict__ prime,
    float* __restrict__ eout, const float* __restrict__ h1,
    float* __restrict__ mapbase, int Nother){
  int i = blockIdx.x;
  int tid = threadIdx.x, lane = tid & 63, w = tid >> 6;
  __shared__ float xrow[HDIM];
  __shared__ float qv[2*HDIM];
  __shared__ float prl[4*304];
  __shared__ float red[4];
  const float* rowp = xa + (size_t)i*HDIM;
  for (int t=tid; t<HDIM;   t+=256) xrow[t] = rowp[t];
  for (int t=tid; t<2*HDIM; t+=256) qv[t]   = h1[t];
  int g = mybatch[i];
  int js = ooff[g], je = ooff[g+1];
  __syncthreads();
  if (WRITE_MAP){
    float* mrow = mapbase + (size_t)i*Nother;
    const vf4 z4 = {0.f,0.f,0.f,0.f};
    int nf4 = Nother >> 2;
    for (int q4=tid; q4<nf4; q4+=256){
      int j0 = q4*4;
      if (j0+4 <= js || j0 >= je){
        __builtin_nontemporal_store(z4, (vf4*)(mrow + j0));
      } else {
        #pragma unroll
        for(int u=0;u<4;u++){ int j=j0+u; if (j<js || j>=je) mrow[j]=0.f; }
      }
    }
  }
  float pr[5];
  #pragma unroll
  for(int c=0;c<5;c++) pr[c]=0.f;
  for (int j = js + w; j < je; j += 4){
    const float* orow = xb + (size_t)j*HDIM;
    float xv[5]; float d = 0.f;
    #pragma unroll
    for(int c=0;c<5;c++){
      int k = lane + 64*c; float x=0.f, a=0.f;
      if (k<HDIM){ x = orow[k]; a = xrow[k]; }
      xv[c]=x; d += a*x;
    }
    d = wred_sum(d);
    if (WRITE_MAP && lane==0) mapbase[(size_t)i*Nother + j] = d;
    #pragma unroll
    for(int c=0;c<5;c++) pr[c] += d * xv[c];
  }
  #pragma unroll
  for(int c=0;c<5;c++){ int k = lane + 64*c; if (k<HDIM) prl[w*304 + k] = pr[c]; }
  __syncthreads();
  float ep = 0.f;
  for (int t=tid; t<HDIM; t+=256){
    float s = prl[t] + prl[304+t] + prl[608+t] + prl[912+t];
    prime[(size_t)i*HDIM + t] = s;
    ep += xrow[t]*qv[t] + s*qv[HDIM+t];
  }
  ep = wred_sum(ep);
  if (lane==0) red[w] = ep;
  __syncthreads();
  if (tid==0) eout[i] = red[0]+red[1]+red[2]+red[3];
}

// ---- K5: segment softmax over e1 + r1 = sum_n a_n * [x_n, prime_n] --------
__global__ __launch_bounds__(256) void k_r1(const float* __restrict__ su,
    const float* __restrict__ sv, const float* __restrict__ spr,
    const float* __restrict__ svp, const float* __restrict__ e1u,
    const float* __restrict__ e1v, const int* __restrict__ uoff,
    const int* __restrict__ voff, float* __restrict__ r1){
  int bs = blockIdx.x; int set = bs >> 8; int g = bs & 255;
  const float* x  = set? sv  : su;
  const float* pr = set? svp : spr;
  const float* e  = set? e1v : e1u;
  const int* off  = set? voff: uoff;
  int tid = threadIdx.x, lane = tid & 63, w = tid >> 6;
  __shared__ float al[2048]; __shared__ float red[4]; __shared__ float shv;
  int ns = off[g], ne = off[g+1]; int n = ne - ns;
  float m = -INFINITY;
  for (int t=ns+tid; t<ne; t+=256) m = fmaxf(m, e[t]);
  m = wred_max(m);
  if (lane==0) red[w]=m;
  __syncthreads();
  if (tid==0) shv = fmaxf(fmaxf(red[0],red[1]),fmaxf(red[2],red[3]));
  __syncthreads();
  float emax = shv;
  float s = 0.f;
  for (int t=tid; t<n; t+=256){ float a = expf(e[ns+t]-emax); if (t<2048) al[t]=a; s += a; }
  s = wred_sum(s);
  __syncthreads();
  if (lane==0) red[w]=s;
  __syncthreads();
  if (tid==0) shv = red[0]+red[1]+red[2]+red[3];
  __syncthreads();
  float inv = 1.f/(shv + 1e-16f);
  float acc[3] = {0.f,0.f,0.f};
  for (int nn=0; nn<n; nn++){
    float a = (nn<2048)? al[nn] : expf(e[ns+nn]-emax);
    const float* xr = x  + (size_t)(ns+nn)*HDIM;
    const float* pp = pr + (size_t)(ns+nn)*HDIM;
    #pragma unroll
    for(int u=0;u<3;u++){ int c = tid + u*256; if (c<DDIM){
        float xv = (c<HDIM)? xr[c] : pp[c-HDIM]; acc[u] += a*xv; } }
  }
  #pragma unroll
  for(int u=0;u<3;u++){ int c = tid + u*256; if (c<DDIM) r1[(size_t)bs*DDIM + c] = acc[u]*inv; }
}

// ---- K6: gbase[n] = b_ih+b_hh + q1·W_ih[n,:600] + h1·W_hh[n,:]  (q1=h1) ----
__global__ __launch_bounds__(256) void k_gbase(const float* __restrict__ h1,
    const float* __restrict__ Wih, const float* __restrict__ Whh,
    const float* __restrict__ b_ih, const float* __restrict__ b_hh,
    float* __restrict__ gbase){
  int n = blockIdx.x*4 + (threadIdx.x >> 6); int lane = threadIdx.x & 63;
  if (n >= 2400) return;
  const float* wi = Wih + (size_t)n*1200;
  const float* wh = Whh + (size_t)n*600;
  float s = 0.f;
  for (int k=lane; k<DDIM; k+=64) s += h1[k]*(wi[k] + wh[k]);
  s = wred_sum(s);
  if (lane==0) gbase[n] = s + b_ih[n] + b_hh[n];
}

// ---- K7: g2[gs][n] = sum_k r1[gs][k]*W_ih[n][600+k]   (512x2400x600) ------
__global__ __launch_bounds__(256) void k_gemm(const float* __restrict__ r1,
    const float* __restrict__ Wih, float* __restrict__ g2){
  __shared__ __align__(16) float Al[16*64];
  __shared__ __align__(16) float Bl[16*64];
  int tid = threadIdx.x;
  int n0 = blockIdx.x*64, gs0 = blockIdx.y*64;
  int tx = tid & 15, ty = tid >> 4;
  int lk = tid & 15, lr = tid >> 4;
  float acc[4][4] = {};
  for (int kt=0; kt<600; kt+=16){
    int k = kt + lk;
    #pragma unroll
    for (int u=0; u<4; u++){
      int gl = lr + u*16;
      Al[lk*64 + gl] = (k<600)? r1[(size_t)(gs0+gl)*DDIM + k] : 0.f;
      int n = n0 + gl;
      Bl[lk*64 + gl] = (k<600 && n<2400)? Wih[(size_t)n*1200 + 600 + k] : 0.f;
    }
    __syncthreads();
    #pragma unroll
    for (int kk=0; kk<16; kk++){
      float4 av = *(const float4*)&Al[kk*64 + ty*4];
      float4 bv = *(const float4*)&Bl[kk*64 + tx*4];
      float a[4]={av.x,av.y,av.z,av.w}, b[4]={bv.x,bv.y,bv.z,bv.w};
      #pragma unroll
      for(int mm=0;mm<4;mm++)
        #pragma unroll
        for(int nn=0;nn<4;nn++) acc[mm][nn] += a[mm]*b[nn];
    }
    __syncthreads();
  }
  #pragma unroll
  for (int mm=0; mm<4; mm++){
    int gs = gs0 + ty*4 + mm;
    int n  = n0 + tx*4;
    if (n+4 <= 2400){
      float4 o = make_float4(acc[mm][0],acc[mm][1],acc[mm][2],acc[mm][3]);
      *(float4*)&g2[(size_t)gs*2400 + n] = o;
    } else {
      #pragma unroll
      for(int nn=0;nn<4;nn++) if (n+nn<2400) g2[(size_t)gs*2400 + n+nn] = acc[mm][nn];
    }
  }
}

// ---- K8: step-2 LSTM pointwise -> h2 --------------------------------------
__global__ __launch_bounds__(256) void k_lstm2(const float* __restrict__ g2,
    const float* __restrict__ gbase, const float* __restrict__ c1,
    float* __restrict__ h2){
  int idx = blockIdx.x*256 + threadIdx.x;
  if (idx >= 512*DDIM) return;
  int gs = idx / DDIM, d = idx - gs*DDIM;
  const float* gg = g2 + (size_t)gs*2400;
  float gi = gg[d]        + gbase[d];
  float gf = gg[600+d]    + gbase[600+d];
  float gG = gg[1200+d]   + gbase[1200+d];
  float go = gg[1800+d]   + gbase[1800+d];
  float c  = sigm(gf)*c1[d] + sigm(gi)*tanhf(gG);
  h2[idx] = sigm(go)*tanhf(c);
}

// ---- K9: e2 = x2·h2[g], segment softmax, r2; emit prediction partials -----
__global__ __launch_bounds__(256) void k_r2(const float* __restrict__ su,
    const float* __restrict__ sv, const float* __restrict__ spr,
    const float* __restrict__ svp, const int* __restrict__ uoff,
    const int* __restrict__ voff, const float* __restrict__ h2,
    const float* __restrict__ pW, float* __restrict__ e2u,
    float* __restrict__ e2v, float* __restrict__ ppart){
  int bs = blockIdx.x; int set = bs >> 8; int g = bs & 255;
  const float* x  = set? sv  : su;
  const float* pr = set? svp : spr;
  const int* off  = set? voff: uoff;
  float* e2       = set? e2v : e2u;
  int tid = threadIdx.x, lane = tid & 63, w = tid >> 6;
  __shared__ float q[DDIM]; __shared__ float al[2048];
  __shared__ float red[4]; __shared__ float shv;
  for (int t=tid; t<DDIM; t+=256) q[t] = h2[(size_t)bs*DDIM + t];
  int ns = off[g], ne = off[g+1]; int n = ne - ns;
  __syncthreads();
  for (int node = ns + w; node < ne; node += 4){
    const float* xr = x  + (size_t)node*HDIM;
    const float* pp = pr + (size_t)node*HDIM;
    float d = 0.f;
    #pragma unroll
    for(int c=0;c<10;c++){ int k = lane + 64*c; if (k<DDIM){
        float xv = (k<HDIM)? xr[k] : pp[k-HDIM]; d += xv*q[k]; } }
    d = wred_sum(d);
    if (lane==0) e2[node] = d;
  }
  __syncthreads();   // block-scope visibility of e2 (same CU L1 path)
  float m = -INFINITY;
  for (int t=ns+tid; t<ne; t+=256) m = fmaxf(m, e2[t]);
  m = wred_max(m);
  if (lane==0) red[w]=m;
  __syncthreads();
  if (tid==0) shv = fmaxf(fmaxf(red[0],red[1]),fmaxf(red[2],red[3]));
  __syncthreads();
  float emax = shv;
  float s = 0.f;
  for (int t=tid; t<n; t+=256){ float a = expf(e2[ns+t]-emax); if (t<2048) al[t]=a; s += a; }
  s = wred_sum(s);
  __syncthreads();
  if (lane==0) red[w]=s;
  __syncthreads();
  if (tid==0) shv = red[0]+red[1]+red[2]+red[3];
  __syncthreads();
  float inv = 1.f/(shv + 1e-16f);
  float acc[3] = {0.f,0.f,0.f};
  for (int nn=0; nn<n; nn++){
    float a = (nn<2048)? al[nn] : expf(e2[ns+nn]-emax);
    const float* xr = x  + (size_t)(ns+nn)*HDIM;
    const float* pp = pr + (size_t)(ns+nn)*HDIM;
    #pragma unroll
    for(int u=0;u<3;u++){ int c = tid + u*256; if (c<DDIM){
        float xv = (c<HDIM)? xr[c] : pp[c-HDIM]; acc[u] += a*xv; } }
  }
  int hoff = set? 1200 : 0;
  float p = 0.f;
  #pragma unroll
  for(int u=0;u<3;u++){ int c = tid + u*256; if (c<DDIM) p += (acc[u]*inv)*pW[hoff+600+c]; }
  for (int t=tid; t<DDIM; t+=256) p += q[t]*pW[hoff+t];
  p = wred_sum(p);
  __syncthreads();
  if (lane==0) red[w] = p;
  __syncthreads();
  if (tid==0) ppart[bs] = red[0]+red[1]+red[2]+red[3];
}

// ---- K10: predictions ------------------------------------------------------
__global__ __launch_bounds__(256) void k_pred(const float* __restrict__ ppart,
    const float* __restrict__ pred_b, float* __restrict__ out){
  int g = threadIdx.x;
  out[g] = ppart[g] + ppart[NGR+g] + pred_b[0];
}

extern "C" void kernel_launch(void* const* d_in, const int* in_sizes, int n_in,
                              void* d_out, int out_size, void* d_ws, size_t ws_size,
                              hipStream_t stream) {
  const float* solute_x  = (const float*)d_in[0];
  const float* solvent_x = (const float*)d_in[1];
  const int*   ub        = (const int*)d_in[2];
  const int*   vb        = (const int*)d_in[3];
  // d_in[4] = num_graphs (device scalar) -- fixed at 256 by setup
  const float* Wih  = (const float*)d_in[5];
  const float* Whh  = (const float*)d_in[6];
  const float* b_ih = (const float*)d_in[7];
  const float* b_hh = (const float*)d_in[8];
  const float* pW   = (const float*)d_in[9];
  const float* pb   = (const float*)d_in[10];

  int Nu = in_sizes[0] / HDIM;
  int Nv = in_sizes[1] / HDIM;

  float* out = (float*)d_out;
  int predn = out_size - Nu*Nv;        // = 256
  float* mapbase = out + predn;

  // workspace layout (floats)
  float* ws = (float*)d_ws;
  float* su    = ws;                     // Nu*300
  float* sv    = su    + (size_t)Nu*HDIM;
  float* spr   = sv    + (size_t)Nv*HDIM;
  float* svp   = spr   + (size_t)Nu*HDIM;
  float* e1u   = svp   + (size_t)Nv*HDIM;  // Nu
  float* e1v   = e1u   + Nu;               // Nv
  float* h1    = e1v   + Nv;               // 600
  float* c1    = h1    + DDIM;             // 600
  float* r1    = c1    + DDIM;             // 512*600
  float* gbase = r1    + 512*DDIM;         // 2400
  float* g2    = gbase + 2400;             // 512*2400
  float* h2    = g2    + (size_t)512*2400; // 512*600
  float* ppart = h2    + 512*DDIM;         // 512
  int*   uoff  = (int*)(ppart + 512);      // 257
  int*   voff  = uoff + 257;               // 257

  k_norm<<<dim3((Nu+Nv)/4), dim3(256), 0, stream>>>(solute_x, solvent_x, su, sv, Nu, Nv);
  k_off_h1<<<dim3(1), dim3(640), 0, stream>>>(ub, vb, Nu, Nv, uoff, voff, b_ih, b_hh, h1, c1);
  k_prime<true ><<<dim3(Nu), dim3(256), 0, stream>>>(su, sv, ub, voff, spr, e1u, h1, mapbase, Nv);
  k_prime<false><<<dim3(Nv), dim3(256), 0, stream>>>(sv, su, vb, uoff, svp, e1v, h1, nullptr, Nv);
  k_r1<<<dim3(512), dim3(256), 0, stream>>>(su, sv, spr, svp, e1u, e1v, uoff, voff, r1);
  k_gbase<<<dim3(600), dim3(256), 0, stream>>>(h1, Wih, Whh, b_ih, b_hh, gbase);
  k_gemm<<<dim3(38, 8), dim3(256), 0, stream>>>(r1, Wih, g2);
  k_lstm2<<<dim3((512*DDIM + 255)/256), dim3(256), 0, stream>>>(g2, gbase, c1, h2);
  k_r2<<<dim3(512), dim3(256), 0, stream>>>(su, sv, spr, svp, uoff, voff, h2, pW, e1u, e1v, ppart);
  k_pred<<<dim3(1), dim3(NGR), 0, stream>>>(ppart, pb, out);
}

// Round 3
// 576.460 us; speedup vs baseline: 1.0250x; 1.0250x over previous
//
#include <hip/hip_runtime.h>
#include <math.h>

// Problem constants: H=300, D=600, B=256 graphs, Nu=Nv=8192, batch SORTED.
#define HDIM 300
#define DDIM 600
#define NGR  256

typedef float vf4 __attribute__((ext_vector_type(4)));

__device__ __forceinline__ float wred_sum(float v){
  #pragma unroll
  for(int o=32;o;o>>=1) v += __shfl_xor(v,o,64);
  return v;
}
__device__ __forceinline__ float wred_max(float v){
  #pragma unroll
  for(int o=32;o;o>>=1) v = fmaxf(v,__shfl_xor(v,o,64));
  return v;
}
__device__ __forceinline__ float sigm(float x){ return 1.f/(1.f+expf(-x)); }

// ---- K1: l2-normalize both node sets; last block does offsets (binary
// search on sorted batch), step-1 LSTM closed form (gates = b_ih+b_hh), and
// out[g] = pred_b init for the atomicAdd prediction path. -------------------
__global__ __launch_bounds__(256) void k_norm_off(const float* __restrict__ xu,
    const float* __restrict__ xv, float* __restrict__ su, float* __restrict__ sv,
    int Nu, int Nv, const int* __restrict__ ub, const int* __restrict__ vb,
    int* __restrict__ uoff, int* __restrict__ voff,
    const float* __restrict__ b_ih, const float* __restrict__ b_hh,
    float* __restrict__ h1, float* __restrict__ c1,
    const float* __restrict__ pb, float* __restrict__ outp){
  if (blockIdx.x == gridDim.x - 1){
    int t = threadIdx.x;
    if (t < NGR){
      int lo=0, hi=Nu;
      while(lo<hi){ int m=(lo+hi)>>1; if (ub[m] < t) lo=m+1; else hi=m; }
      uoff[t]=lo;
      lo=0; hi=Nv;
      while(lo<hi){ int m=(lo+hi)>>1; if (vb[m] < t) lo=m+1; else hi=m; }
      voff[t]=lo;
      if (t==0){ uoff[NGR]=Nu; voff[NGR]=Nv; }
      outp[t] = pb[0];
    }
    for (int d=threadIdx.x; d<DDIM; d+=256){
      float gi = b_ih[d]      + b_hh[d];
      float gg = b_ih[1200+d] + b_hh[1200+d];
      float go = b_ih[1800+d] + b_hh[1800+d];
      float c  = sigm(gi)*tanhf(gg);       // f*c0 = 0
      c1[d]=c; h1[d]=sigm(go)*tanhf(c);
    }
    return;
  }
  int wid = blockIdx.x*4 + (threadIdx.x >> 6);
  int lane = threadIdx.x & 63;
  const float* src; float* dst;
  if (wid < Nu){ src = xu + (size_t)wid*HDIM; dst = su + (size_t)wid*HDIM; }
  else         { src = xv + (size_t)(wid-Nu)*HDIM; dst = sv + (size_t)(wid-Nu)*HDIM; }
  const vf4* s4 = (const vf4*)src;
  vf4 A = s4[lane];
  vf4 Bv = (lane<11)? s4[64+lane] : (vf4){0.f,0.f,0.f,0.f};
  float s = A.x*A.x+A.y*A.y+A.z*A.z+A.w*A.w + Bv.x*Bv.x+Bv.y*Bv.y+Bv.z*Bv.z+Bv.w*Bv.w;
  s = wred_sum(s);
  float inv = 1.f / fmaxf(sqrtf(s), 1e-12f);
  vf4* d4 = (vf4*)dst;
  d4[lane] = A*inv;
  if (lane<11) d4[64+lane] = Bv*inv;
}

// ---- K2: merged per-row kernel (blocks [0,Nu)=solute write map; [Nu,..)=
// solvent). Zero-fill map row (NT float4), in-graph dots, prime accumulation,
// e1 = [row,prime]·q1. ------------------------------------------------------
__global__ __launch_bounds__(256) void k_prime(const float* __restrict__ su,
    const float* __restrict__ sv, const int* __restrict__ ub,
    const int* __restrict__ vb, const int* __restrict__ uoff,
    const int* __restrict__ voff, float* __restrict__ spr,
    float* __restrict__ svp, float* __restrict__ e1u, float* __restrict__ e1v,
    const float* __restrict__ h1, float* __restrict__ mapbase, int Nu, int Nv){
  int b = blockIdx.x;
  bool isU = (b < Nu);
  int i = isU ? b : b - Nu;
  const float* xa = isU ? su : sv;
  const float* xb = isU ? sv : su;
  const int* mybatch = isU ? ub : vb;
  const int* ooff    = isU ? voff : uoff;
  float* prime = isU ? spr : svp;
  float* eout  = isU ? e1u : e1v;

  int tid = threadIdx.x, lane = tid & 63, w = tid >> 6;
  __shared__ __align__(16) float xrow[304];
  __shared__ __align__(16) float prl[4*304];
  __shared__ float qv[2*HDIM];
  __shared__ float red[4];
  const float* rowp = xa + (size_t)i*HDIM;
  for (int t=tid; t<HDIM;   t+=256) xrow[t] = rowp[t];
  for (int t=tid; t<2*HDIM; t+=256) qv[t]   = h1[t];
  int g = mybatch[i];
  int js = ooff[g], je = ooff[g+1];
  __syncthreads();

  if (isU){  // zero-fill the map row except the in-graph span
    float* mrow = mapbase + (size_t)i*Nv;
    const vf4 z4 = {0.f,0.f,0.f,0.f};
    int nf4 = Nv >> 2;
    for (int q4=tid; q4<nf4; q4+=256){
      int j0 = q4*4;
      if (j0+4 <= js || j0 >= je){
        __builtin_nontemporal_store(z4, (vf4*)(mrow + j0));
      } else {
        #pragma unroll
        for(int u=0;u<4;u++){ int j=j0+u; if (j<js || j>=je) mrow[j]=0.f; }
      }
    }
  }

  const vf4* x4 = (const vf4*)xrow;
  vf4 xA = x4[lane];
  vf4 xB = (lane<11)? x4[64+lane] : (vf4){0.f,0.f,0.f,0.f};
  vf4 prA = {0.f,0.f,0.f,0.f}, prB = {0.f,0.f,0.f,0.f};
  for (int j = js + w; j < je; j += 4){
    const vf4* orow = (const vf4*)(xb + (size_t)j*HDIM);
    vf4 oA = orow[lane];
    vf4 oB = (lane<11)? orow[64+lane] : (vf4){0.f,0.f,0.f,0.f};
    float d = oA.x*xA.x + oA.y*xA.y + oA.z*xA.z + oA.w*xA.w
            + oB.x*xB.x + oB.y*xB.y + oB.z*xB.z + oB.w*xB.w;
    d = wred_sum(d);
    if (isU && lane==0) mapbase[(size_t)i*Nv + j] = d;
    prA += d * oA;
    prB += d * oB;
  }
  vf4* p4 = (vf4*)(prl + w*304);
  p4[lane] = prA;
  if (lane<11) p4[64+lane] = prB;
  __syncthreads();
  float ep = 0.f;
  for (int t=tid; t<HDIM; t+=256){
    float s = prl[t] + prl[304+t] + prl[608+t] + prl[912+t];
    prime[(size_t)i*HDIM + t] = s;
    ep += xrow[t]*qv[t] + s*qv[HDIM+t];
  }
  ep = wred_sum(ep);
  if (lane==0) red[w] = ep;
  __syncthreads();
  if (tid==0) eout[i] = red[0]+red[1]+red[2]+red[3];
}

// ---- K3: blocks [0,512): segment softmax + r1. blocks [512,1112): gbase ---
__global__ __launch_bounds__(256) void k_r1_gbase(const float* __restrict__ su,
    const float* __restrict__ sv, const float* __restrict__ spr,
    const float* __restrict__ svp, const float* __restrict__ e1u,
    const float* __restrict__ e1v, const int* __restrict__ uoff,
    const int* __restrict__ voff, float* __restrict__ r1,
    const float* __restrict__ h1, const float* __restrict__ Wih,
    const float* __restrict__ Whh, const float* __restrict__ b_ih,
    const float* __restrict__ b_hh, float* __restrict__ gbase){
  int tid = threadIdx.x, lane = tid & 63, w = tid >> 6;
  if (blockIdx.x >= 512){
    int n = (blockIdx.x - 512)*4 + w;
    if (n >= 2400) return;
    const float* wi = Wih + (size_t)n*1200;
    const float* wh = Whh + (size_t)n*600;
    float s = 0.f;
    for (int k=lane; k<DDIM; k+=64) s += h1[k]*(wi[k] + wh[k]);
    s = wred_sum(s);
    if (lane==0) gbase[n] = s + b_ih[n] + b_hh[n];
    return;
  }
  int bs = blockIdx.x; int set = bs >> 8; int g = bs & 255;
  const float* x  = set? sv  : su;
  const float* pr = set? svp : spr;
  const float* e  = set? e1v : e1u;
  const int* off  = set? voff: uoff;
  __shared__ float al[2048]; __shared__ float red[4]; __shared__ float shv;
  int ns = off[g], ne = off[g+1]; int n = ne - ns;
  float m = -INFINITY;
  for (int t=ns+tid; t<ne; t+=256) m = fmaxf(m, e[t]);
  m = wred_max(m);
  if (lane==0) red[w]=m;
  __syncthreads();
  if (tid==0) shv = fmaxf(fmaxf(red[0],red[1]),fmaxf(red[2],red[3]));
  __syncthreads();
  float emax = shv;
  float s = 0.f;
  for (int t=tid; t<n; t+=256){ float a = expf(e[ns+t]-emax); if (t<2048) al[t]=a; s += a; }
  s = wred_sum(s);
  __syncthreads();
  if (lane==0) red[w]=s;
  __syncthreads();
  if (tid==0) shv = red[0]+red[1]+red[2]+red[3];
  __syncthreads();
  float inv = 1.f/(shv + 1e-16f);
  float acc[3] = {0.f,0.f,0.f};
  for (int nn=0; nn<n; nn++){
    float a = (nn<2048)? al[nn] : expf(e[ns+nn]-emax);
    const float* xr = x  + (size_t)(ns+nn)*HDIM;
    const float* pp = pr + (size_t)(ns+nn)*HDIM;
    #pragma unroll
    for(int u=0;u<3;u++){ int c = tid + u*256; if (c<DDIM){
        float xv = (c<HDIM)? xr[c] : pp[c-HDIM]; acc[u] += a*xv; } }
  }
  #pragma unroll
  for(int u=0;u<3;u++){ int c = tid + u*256; if (c<DDIM) r1[(size_t)bs*DDIM + c] = acc[u]*inv; }
}

// ---- K4: fused GEMM (g2 = r1 @ Wih[:,600:].T) + step-2 LSTM pointwise.
// Block = 64 gs x 16 d x 4 gates (= 64x64 GEMM tile); gates go through LDS,
// h2 written directly (no g2 buffer). LDS stride 68: staging writes (4k+row)%32
// -> 2-way (free) vs the previous 16-way conflict at stride 64. -------------
__global__ __launch_bounds__(256) void k_gemm_lstm(const float* __restrict__ r1,
    const float* __restrict__ Wih, const float* __restrict__ gbase,
    const float* __restrict__ c1, float* __restrict__ h2){
  __shared__ __align__(16) float smem[64*68];   // gates; Al/Bl aliased below
  float* Al = smem;            // 16*68
  float* Bl = smem + 16*68;    // 16*68
  int tid = threadIdx.x;
  int d0  = blockIdx.x*16;     // 38 blocks: d0 = 0..592 (last has 8 valid)
  int gs0 = blockIdx.y*64;
  int tx = tid & 15, ty = tid >> 4;
  int lk = tid & 15, lr = tid >> 4;
  float acc[4][4] = {};
  for (int kt=0; kt<600; kt+=16){
    int k = kt + lk;
    bool kok = (k < 600);
    #pragma unroll
    for (int u=0; u<4; u++){
      int rl = lr + u*16;                   // 0..63
      Al[lk*68 + rl] = kok ? r1[(size_t)(gs0+rl)*DDIM + k] : 0.f;
      int gate = rl >> 4, dd = rl & 15;
      int d = d0 + dd;
      Bl[lk*68 + rl] = (kok && d < 600)
          ? Wih[(size_t)(gate*600 + d)*1200 + 600 + k] : 0.f;
    }
    __syncthreads();
    #pragma unroll
    for (int kk=0; kk<16; kk++){
      vf4 av = ((const vf4*)(Al + kk*68))[ty];
      vf4 bv = ((const vf4*)(Bl + kk*68))[tx];
      float a[4]={av.x,av.y,av.z,av.w}, bb[4]={bv.x,bv.y,bv.z,bv.w};
      #pragma unroll
      for(int mm=0;mm<4;mm++)
        #pragma unroll
        for(int nn=0;nn<4;nn++) acc[mm][nn] += a[mm]*bb[nn];
    }
    __syncthreads();
  }
  // write gates to LDS: gates[row_local * 68 + col], col = gate*16 + dd
  #pragma unroll
  for (int mm=0; mm<4; mm++){
    vf4 o = {acc[mm][0], acc[mm][1], acc[mm][2], acc[mm][3]};
    ((vf4*)(smem + (ty*4+mm)*68))[tx] = o;
  }
  __syncthreads();
  // LSTM pointwise: thread handles d_l = tid&15, rows tid>>4 + u*16
  int d_l = tid & 15, r0 = tid >> 4;
  int d = d0 + d_l;
  if (d < 600){
    float gb_i = gbase[d], gb_f = gbase[600+d], gb_g = gbase[1200+d], gb_o = gbase[1800+d];
    float cc1 = c1[d];
    #pragma unroll
    for (int u=0; u<4; u++){
      int rl = r0 + u*16;
      const float* gr = smem + rl*68;
      float gi = gr[d_l]      + gb_i;
      float gf = gr[16+d_l]   + gb_f;
      float gG = gr[32+d_l]   + gb_g;
      float go = gr[48+d_l]   + gb_o;
      float c  = sigm(gf)*cc1 + sigm(gi)*tanhf(gG);
      h2[(size_t)(gs0+rl)*DDIM + d] = sigm(go)*tanhf(c);
    }
  }
}

// ---- K5: e2 = x2·h2[g], segment softmax, r2; atomicAdd prediction ---------
__global__ __launch_bounds__(256) void k_r2(const float* __restrict__ su,
    const float* __restrict__ sv, const float* __restrict__ spr,
    const float* __restrict__ svp, const int* __restrict__ uoff,
    const int* __restrict__ voff, const float* __restrict__ h2,
    const float* __restrict__ pW, float* __restrict__ e2u,
    float* __restrict__ e2v, float* __restrict__ outp){
  int bs = blockIdx.x; int set = bs >> 8; int g = bs & 255;
  const float* x  = set? sv  : su;
  const float* pr = set? svp : spr;
  const int* off  = set? voff: uoff;
  float* e2       = set? e2v : e2u;
  int tid = threadIdx.x, lane = tid & 63, w = tid >> 6;
  __shared__ float q[DDIM]; __shared__ float al[2048];
  __shared__ float red[4]; __shared__ float shv;
  for (int t=tid; t<DDIM; t+=256) q[t] = h2[(size_t)bs*DDIM + t];
  int ns = off[g], ne = off[g+1]; int n = ne - ns;
  __syncthreads();
  for (int node = ns + w; node < ne; node += 4){
    const float* xr = x  + (size_t)node*HDIM;
    const float* pp = pr + (size_t)node*HDIM;
    float d = 0.f;
    #pragma unroll
    for(int c=0;c<10;c++){ int k = lane + 64*c; if (k<DDIM){
        float xv = (k<HDIM)? xr[k] : pp[k-HDIM]; d += xv*q[k]; } }
    d = wred_sum(d);
    if (lane==0) e2[node] = d;
  }
  __syncthreads();
  float m = -INFINITY;
  for (int t=ns+tid; t<ne; t+=256) m = fmaxf(m, e2[t]);
  m = wred_max(m);
  if (lane==0) red[w]=m;
  __syncthreads();
  if (tid==0) shv = fmaxf(fmaxf(red[0],red[1]),fmaxf(red[2],red[3]));
  __syncthreads();
  float emax = shv;
  float s = 0.f;
  for (int t=tid; t<n; t+=256){ float a = expf(e2[ns+t]-emax); if (t<2048) al[t]=a; s += a; }
  s = wred_sum(s);
  __syncthreads();
  if (lane==0) red[w]=s;
  __syncthreads();
  if (tid==0) shv = red[0]+red[1]+red[2]+red[3];
  __syncthreads();
  float inv = 1.f/(shv + 1e-16f);
  float acc[3] = {0.f,0.f,0.f};
  for (int nn=0; nn<n; nn++){
    float a = (nn<2048)? al[nn] : expf(e2[ns+nn]-emax);
    const float* xr = x  + (size_t)(ns+nn)*HDIM;
    const float* pp = pr + (size_t)(ns+nn)*HDIM;
    #pragma unroll
    for(int u=0;u<3;u++){ int c = tid + u*256; if (c<DDIM){
        float xv = (c<HDIM)? xr[c] : pp[c-HDIM]; acc[u] += a*xv; } }
  }
  int hoff = set? 1200 : 0;
  float p = 0.f;
  #pragma unroll
  for(int u=0;u<3;u++){ int c = tid + u*256; if (c<DDIM) p += (acc[u]*inv)*pW[hoff+600+c]; }
  for (int t=tid; t<DDIM; t+=256) p += q[t]*pW[hoff+t];
  p = wred_sum(p);
  __syncthreads();
  if (lane==0) red[w] = p;
  __syncthreads();
  if (tid==0) atomicAdd(&outp[g], red[0]+red[1]+red[2]+red[3]);
}

extern "C" void kernel_launch(void* const* d_in, const int* in_sizes, int n_in,
                              void* d_out, int out_size, void* d_ws, size_t ws_size,
                              hipStream_t stream) {
  const float* solute_x  = (const float*)d_in[0];
  const float* solvent_x = (const float*)d_in[1];
  const int*   ub        = (const int*)d_in[2];
  const int*   vb        = (const int*)d_in[3];
  const float* Wih  = (const float*)d_in[5];
  const float* Whh  = (const float*)d_in[6];
  const float* b_ih = (const float*)d_in[7];
  const float* b_hh = (const float*)d_in[8];
  const float* pW   = (const float*)d_in[9];
  const float* pb   = (const float*)d_in[10];

  int Nu = in_sizes[0] / HDIM;
  int Nv = in_sizes[1] / HDIM;

  float* out = (float*)d_out;
  int predn = out_size - Nu*Nv;        // = 256
  float* mapbase = out + predn;

  float* ws = (float*)d_ws;
  float* su    = ws;
  float* sv    = su    + (size_t)Nu*HDIM;
  float* spr   = sv    + (size_t)Nv*HDIM;
  float* svp   = spr   + (size_t)Nu*HDIM;
  float* e1u   = svp   + (size_t)Nv*HDIM;  // Nu
  float* e1v   = e1u   + Nu;               // Nv
  float* h1    = e1v   + Nv;               // 600
  float* c1    = h1    + DDIM;             // 600
  float* r1    = c1    + DDIM;             // 512*600
  float* gbase = r1    + 512*DDIM;         // 2400
  float* h2    = gbase + 2400;             // 512*600
  int*   uoff  = (int*)(h2 + 512*DDIM);    // 257
  int*   voff  = uoff + 257;               // 257

  k_norm_off<<<dim3((Nu+Nv)/4 + 1), dim3(256), 0, stream>>>(
      solute_x, solvent_x, su, sv, Nu, Nv, ub, vb, uoff, voff,
      b_ih, b_hh, h1, c1, pb, out);
  k_prime<<<dim3(Nu+Nv), dim3(256), 0, stream>>>(
      su, sv, ub, vb, uoff, voff, spr, svp, e1u, e1v, h1, mapbase, Nu, Nv);
  k_r1_gbase<<<dim3(512+600), dim3(256), 0, stream>>>(
      su, sv, spr, svp, e1u, e1v, uoff, voff, r1, h1, Wih, Whh, b_ih, b_hh, gbase);
  k_gemm_lstm<<<dim3(38, 8), dim3(256), 0, stream>>>(r1, Wih, gbase, c1, h2);
  k_r2<<<dim3(512), dim3(256), 0, stream>>>(
      su, sv, spr, svp, uoff, voff, h2, pW, e1u, e1v, out);
}

// Round 4
// 548.620 us; speedup vs baseline: 1.0771x; 1.0507x over previous
//
#include <hip/hip_runtime.h>
#include <math.h>

// Problem constants: H=300, D=600, B=256 graphs, Nu=Nv=8192, batch SORTED.
#define HDIM 300
#define DDIM 600
#define NGR  256

typedef float vf4 __attribute__((ext_vector_type(4)));
typedef float vf2 __attribute__((ext_vector_type(2)));

__device__ __forceinline__ float wred_sum(float v){
  #pragma unroll
  for(int o=32;o;o>>=1) v += __shfl_xor(v,o,64);
  return v;
}
__device__ __forceinline__ float wred_max(float v){
  #pragma unroll
  for(int o=32;o;o>>=1) v = fmaxf(v,__shfl_xor(v,o,64));
  return v;
}
__device__ __forceinline__ float sigm(float x){ return 1.f/(1.f+expf(-x)); }

// ---- K1: three roles by blockIdx:
//  [0, NBn)            l2-normalize rows of both node sets (4 waves/block)
//  NBn                 offsets (binary search), step-1 LSTM closed form, out init
//  (NBn, NBn+Nu]       zero-fill map row i outside its in-graph span
// Fill blocks binary-search vb directly (no dependency on the offsets block).
__global__ __launch_bounds__(256) void k_norm_fill_off(const float* __restrict__ xu,
    const float* __restrict__ xv, float* __restrict__ su, float* __restrict__ sv,
    int Nu, int Nv, const int* __restrict__ ub, const int* __restrict__ vb,
    int* __restrict__ uoff, int* __restrict__ voff,
    const float* __restrict__ b_ih, const float* __restrict__ b_hh,
    float* __restrict__ h1, float* __restrict__ c1,
    const float* __restrict__ pb, float* __restrict__ outp,
    float* __restrict__ mapbase){
  int NBn = (Nu + Nv) >> 2;
  int b = blockIdx.x;
  if (b == NBn){
    int t = threadIdx.x;
    if (t < NGR){
      int lo=0, hi=Nu;
      while(lo<hi){ int m=(lo+hi)>>1; if (ub[m] < t) lo=m+1; else hi=m; }
      uoff[t]=lo;
      lo=0; hi=Nv;
      while(lo<hi){ int m=(lo+hi)>>1; if (vb[m] < t) lo=m+1; else hi=m; }
      voff[t]=lo;
      if (t==0){ uoff[NGR]=Nu; voff[NGR]=Nv; }
      outp[t] = pb[0];
    }
    for (int d=threadIdx.x; d<DDIM; d+=256){
      float gi = b_ih[d]      + b_hh[d];
      float gg = b_ih[1200+d] + b_hh[1200+d];
      float go = b_ih[1800+d] + b_hh[1800+d];
      float c  = sigm(gi)*tanhf(gg);       // f*c0 = 0
      c1[d]=c; h1[d]=sigm(go)*tanhf(c);
    }
    return;
  }
  if (b > NBn){
    int i = b - NBn - 1;                   // map row
    int g = ub[i];
    int lo=0, hi=Nv;
    while(lo<hi){ int m=(lo+hi)>>1; if (vb[m] < g) lo=m+1; else hi=m; }
    int js = lo;
    hi = Nv;
    while(lo<hi){ int m=(lo+hi)>>1; if (vb[m] <= g) lo=m+1; else hi=m; }
    int je = lo;
    float* mrow = mapbase + (size_t)i*Nv;
    const vf4 z4 = {0.f,0.f,0.f,0.f};
    int nf4 = Nv >> 2;
    for (int q4=threadIdx.x; q4<nf4; q4+=256){
      int j0 = q4*4;
      if (j0+4 <= js || j0 >= je){
        __builtin_nontemporal_store(z4, (vf4*)(mrow + j0));
      } else {
        #pragma unroll
        for(int u=0;u<4;u++){ int j=j0+u; if (j<js || j>=je) mrow[j]=0.f; }
      }
    }
    return;
  }
  int wid = b*4 + (threadIdx.x >> 6);
  int lane = threadIdx.x & 63;
  const float* src; float* dst;
  if (wid < Nu){ src = xu + (size_t)wid*HDIM; dst = su + (size_t)wid*HDIM; }
  else         { src = xv + (size_t)(wid-Nu)*HDIM; dst = sv + (size_t)(wid-Nu)*HDIM; }
  const vf4* s4 = (const vf4*)src;
  vf4 A = s4[lane];
  vf4 Bv = (lane<11)? s4[64+lane] : (vf4){0.f,0.f,0.f,0.f};
  float s = A.x*A.x+A.y*A.y+A.z*A.z+A.w*A.w + Bv.x*Bv.x+Bv.y*Bv.y+Bv.z*Bv.z+Bv.w*Bv.w;
  s = wred_sum(s);
  float inv = 1.f / fmaxf(sqrtf(s), 1e-12f);
  vf4* d4 = (vf4*)dst;
  d4[lane] = A*inv;
  if (lane<11) d4[64+lane] = Bv*inv;
}

// ---- K2: per-row prime kernel (blocks [0,Nu)=solute, write map dots;
// [Nu,..)=solvent). In-graph dots, prime accumulation, e1 = [row,prime]·q1. --
__global__ __launch_bounds__(256) void k_prime(const float* __restrict__ su,
    const float* __restrict__ sv, const int* __restrict__ ub,
    const int* __restrict__ vb, const int* __restrict__ uoff,
    const int* __restrict__ voff, float* __restrict__ spr,
    float* __restrict__ svp, float* __restrict__ e1u, float* __restrict__ e1v,
    const float* __restrict__ h1, float* __restrict__ mapbase, int Nu, int Nv){
  int b = blockIdx.x;
  bool isU = (b < Nu);
  int i = isU ? b : b - Nu;
  const float* xa = isU ? su : sv;
  const float* xb = isU ? sv : su;
  const int* mybatch = isU ? ub : vb;
  const int* ooff    = isU ? voff : uoff;
  float* prime = isU ? spr : svp;
  float* eout  = isU ? e1u : e1v;

  int tid = threadIdx.x, lane = tid & 63, w = tid >> 6;
  __shared__ __align__(16) float xrow[304];
  __shared__ __align__(16) float prl[4*304];
  __shared__ float qv[2*HDIM];
  __shared__ float red[4];
  const float* rowp = xa + (size_t)i*HDIM;
  for (int t=tid; t<HDIM;   t+=256) xrow[t] = rowp[t];
  for (int t=tid; t<2*HDIM; t+=256) qv[t]   = h1[t];
  int g = mybatch[i];
  int js = ooff[g], je = ooff[g+1];
  __syncthreads();

  const vf4* x4 = (const vf4*)xrow;
  vf4 xA = x4[lane];
  vf4 xB = (lane<11)? x4[64+lane] : (vf4){0.f,0.f,0.f,0.f};
  vf4 prA = {0.f,0.f,0.f,0.f}, prB = {0.f,0.f,0.f,0.f};
  for (int j = js + w; j < je; j += 4){
    const vf4* orow = (const vf4*)(xb + (size_t)j*HDIM);
    vf4 oA = orow[lane];
    vf4 oB = (lane<11)? orow[64+lane] : (vf4){0.f,0.f,0.f,0.f};
    float d = oA.x*xA.x + oA.y*xA.y + oA.z*xA.z + oA.w*xA.w
            + oB.x*xB.x + oB.y*xB.y + oB.z*xB.z + oB.w*xB.w;
    d = wred_sum(d);
    if (isU && lane==0) mapbase[(size_t)i*Nv + j] = d;
    prA += d * oA;
    prB += d * oB;
  }
  vf4* p4 = (vf4*)(prl + w*304);
  p4[lane] = prA;
  if (lane<11) p4[64+lane] = prB;
  __syncthreads();
  float ep = 0.f;
  for (int t=tid; t<HDIM; t+=256){
    float s = prl[t] + prl[304+t] + prl[608+t] + prl[912+t];
    prime[(size_t)i*HDIM + t] = s;
    ep += xrow[t]*qv[t] + s*qv[HDIM+t];
  }
  ep = wred_sum(ep);
  if (lane==0) red[w] = ep;
  __syncthreads();
  if (tid==0) eout[i] = red[0]+red[1]+red[2]+red[3];
}

// ---- K3: blocks [0,512): segment softmax + r1. blocks [512,1112): gbase ---
__global__ __launch_bounds__(256) void k_r1_gbase(const float* __restrict__ su,
    const float* __restrict__ sv, const float* __restrict__ spr,
    const float* __restrict__ svp, const float* __restrict__ e1u,
    const float* __restrict__ e1v, const int* __restrict__ uoff,
    const int* __restrict__ voff, float* __restrict__ r1,
    const float* __restrict__ h1, const float* __restrict__ Wih,
    const float* __restrict__ Whh, const float* __restrict__ b_ih,
    const float* __restrict__ b_hh, float* __restrict__ gbase){
  int tid = threadIdx.x, lane = tid & 63, w = tid >> 6;
  if (blockIdx.x >= 512){
    int n = (blockIdx.x - 512)*4 + w;
    if (n >= 2400) return;
    const float* wi = Wih + (size_t)n*1200;
    const float* wh = Whh + (size_t)n*600;
    float s = 0.f;
    for (int k=lane; k<DDIM; k+=64) s += h1[k]*(wi[k] + wh[k]);
    s = wred_sum(s);
    if (lane==0) gbase[n] = s + b_ih[n] + b_hh[n];
    return;
  }
  int bs = blockIdx.x; int set = bs >> 8; int g = bs & 255;
  const float* x  = set? sv  : su;
  const float* pr = set? svp : spr;
  const float* e  = set? e1v : e1u;
  const int* off  = set? voff: uoff;
  __shared__ float al[2048]; __shared__ float red[4]; __shared__ float shv;
  int ns = off[g], ne = off[g+1]; int n = ne - ns;
  float m = -INFINITY;
  for (int t=ns+tid; t<ne; t+=256) m = fmaxf(m, e[t]);
  m = wred_max(m);
  if (lane==0) red[w]=m;
  __syncthreads();
  if (tid==0) shv = fmaxf(fmaxf(red[0],red[1]),fmaxf(red[2],red[3]));
  __syncthreads();
  float emax = shv;
  float s = 0.f;
  for (int t=tid; t<n; t+=256){ float a = expf(e[ns+t]-emax); if (t<2048) al[t]=a; s += a; }
  s = wred_sum(s);
  __syncthreads();
  if (lane==0) red[w]=s;
  __syncthreads();
  if (tid==0) shv = red[0]+red[1]+red[2]+red[3];
  __syncthreads();
  float inv = 1.f/(shv + 1e-16f);
  float acc[3] = {0.f,0.f,0.f};
  for (int nn=0; nn<n; nn++){
    float a = (nn<2048)? al[nn] : expf(e[ns+nn]-emax);
    const float* xr = x  + (size_t)(ns+nn)*HDIM;
    const float* pp = pr + (size_t)(ns+nn)*HDIM;
    #pragma unroll
    for(int u=0;u<3;u++){ int c = tid + u*256; if (c<DDIM){
        float xv = (c<HDIM)? xr[c] : pp[c-HDIM]; acc[u] += a*xv; } }
  }
  #pragma unroll
  for(int u=0;u<3;u++){ int c = tid + u*256; if (c<DDIM) r1[(size_t)bs*DDIM + c] = acc[u]*inv; }
}

// ---- K4: fused GEMM (gates = r1 @ Wih[:,600:].T) + step-2 LSTM pointwise.
// 32 gs x 64 col tile (cols = 4 gates x 16 d), grid 38x16 = 608 blocks
// (~2.4 blocks/CU vs 1.2 at 64-row tiles). Gates go through LDS; h2 written
// directly. LDS strides 36/68 keep staging stores at 2-way (free). ----------
__global__ __launch_bounds__(256) void k_gemm_lstm(const float* __restrict__ r1,
    const float* __restrict__ Wih, const float* __restrict__ gbase,
    const float* __restrict__ c1, float* __restrict__ h2){
  __shared__ __align__(16) float smem[32*68];   // gates phase; K phase aliases
  float* Al = smem;            // 16*36
  float* Bl = smem + 16*36;    // 16*68
  int tid = threadIdx.x;
  int d0  = blockIdx.x*16;     // 38 blocks: d0 = 0..592 (last has 8 valid)
  int gs0 = blockIdx.y*32;
  int tx = tid & 15, ty = tid >> 4;
  float acc[2][4] = {};
  for (int kt=0; kt<600; kt+=16){
    int k = kt + tx;           // staging: lk = tx, lr = ty
    bool kok = (k < 600);
    #pragma unroll
    for (int u=0; u<2; u++){
      int rl = ty + u*16;
      Al[tx*36 + rl] = kok ? r1[(size_t)(gs0+rl)*DDIM + k] : 0.f;
    }
    #pragma unroll
    for (int u=0; u<4; u++){
      int cl = ty + u*16;                 // 0..63
      int gate = cl >> 4, dd = cl & 15;
      int d = d0 + dd;
      Bl[tx*68 + cl] = (kok && d < 600)
          ? Wih[(size_t)(gate*600 + d)*1200 + 600 + k] : 0.f;
    }
    __syncthreads();
    #pragma unroll
    for (int kk=0; kk<16; kk++){
      vf2 av = ((const vf2*)(Al + kk*36))[ty];
      vf4 bv = ((const vf4*)(Bl + kk*68))[tx];
      float a[2]={av.x,av.y}, bb[4]={bv.x,bv.y,bv.z,bv.w};
      #pragma unroll
      for(int mm=0;mm<2;mm++)
        #pragma unroll
        for(int nn=0;nn<4;nn++) acc[mm][nn] += a[mm]*bb[nn];
    }
    __syncthreads();
  }
  // gates to LDS: gates[row_local * 68 + col], col = gate*16 + dd
  #pragma unroll
  for (int mm=0; mm<2; mm++){
    vf4 o = {acc[mm][0], acc[mm][1], acc[mm][2], acc[mm][3]};
    ((vf4*)(smem + (ty*2+mm)*68))[tx] = o;
  }
  __syncthreads();
  int d_l = tid & 15, r0 = tid >> 4;
  int d = d0 + d_l;
  if (d < 600){
    float gb_i = gbase[d], gb_f = gbase[600+d], gb_g = gbase[1200+d], gb_o = gbase[1800+d];
    float cc1 = c1[d];
    #pragma unroll
    for (int u=0; u<2; u++){
      int rl = r0 + u*16;
      const float* gr = smem + rl*68;
      float gi = gr[d_l]      + gb_i;
      float gf = gr[16+d_l]   + gb_f;
      float gG = gr[32+d_l]   + gb_g;
      float go = gr[48+d_l]   + gb_o;
      float c  = sigm(gf)*cc1 + sigm(gi)*tanhf(gG);
      h2[(size_t)(gs0+rl)*DDIM + d] = sigm(go)*tanhf(c);
    }
  }
}

// ---- K5: e2 = x2·h2[g], segment softmax, r2; atomicAdd prediction ---------
__global__ __launch_bounds__(256) void k_r2(const float* __restrict__ su,
    const float* __restrict__ sv, const float* __restrict__ spr,
    const float* __restrict__ svp, const int* __restrict__ uoff,
    const int* __restrict__ voff, const float* __restrict__ h2,
    const float* __restrict__ pW, float* __restrict__ e2u,
    float* __restrict__ e2v, float* __restrict__ outp){
  int bs = blockIdx.x; int set = bs >> 8; int g = bs & 255;
  const float* x  = set? sv  : su;
  const float* pr = set? svp : spr;
  const int* off  = set? voff: uoff;
  float* e2       = set? e2v : e2u;
  int tid = threadIdx.x, lane = tid & 63, w = tid >> 6;
  __shared__ float q[DDIM]; __shared__ float al[2048];
  __shared__ float red[4]; __shared__ float shv;
  for (int t=tid; t<DDIM; t+=256) q[t] = h2[(size_t)bs*DDIM + t];
  int ns = off[g], ne = off[g+1]; int n = ne - ns;
  __syncthreads();
  for (int node = ns + w; node < ne; node += 4){
    const float* xr = x  + (size_t)node*HDIM;
    const float* pp = pr + (size_t)node*HDIM;
    float d = 0.f;
    #pragma unroll
    for(int c=0;c<10;c++){ int k = lane + 64*c; if (k<DDIM){
        float xv = (k<HDIM)? xr[k] : pp[k-HDIM]; d += xv*q[k]; } }
    d = wred_sum(d);
    if (lane==0) e2[node] = d;
  }
  __syncthreads();
  float m = -INFINITY;
  for (int t=ns+tid; t<ne; t+=256) m = fmaxf(m, e2[t]);
  m = wred_max(m);
  if (lane==0) red[w]=m;
  __syncthreads();
  if (tid==0) shv = fmaxf(fmaxf(red[0],red[1]),fmaxf(red[2],red[3]));
  __syncthreads();
  float emax = shv;
  float s = 0.f;
  for (int t=tid; t<n; t+=256){ float a = expf(e2[ns+t]-emax); if (t<2048) al[t]=a; s += a; }
  s = wred_sum(s);
  __syncthreads();
  if (lane==0) red[w]=s;
  __syncthreads();
  if (tid==0) shv = red[0]+red[1]+red[2]+red[3];
  __syncthreads();
  float inv = 1.f/(shv + 1e-16f);
  float acc[3] = {0.f,0.f,0.f};
  for (int nn=0; nn<n; nn++){
    float a = (nn<2048)? al[nn] : expf(e2[ns+nn]-emax);
    const float* xr = x  + (size_t)(ns+nn)*HDIM;
    const float* pp = pr + (size_t)(ns+nn)*HDIM;
    #pragma unroll
    for(int u=0;u<3;u++){ int c = tid + u*256; if (c<DDIM){
        float xv = (c<HDIM)? xr[c] : pp[c-HDIM]; acc[u] += a*xv; } }
  }
  int hoff = set? 1200 : 0;
  float p = 0.f;
  #pragma unroll
  for(int u=0;u<3;u++){ int c = tid + u*256; if (c<DDIM) p += (acc[u]*inv)*pW[hoff+600+c]; }
  for (int t=tid; t<DDIM; t+=256) p += q[t]*pW[hoff+t];
  p = wred_sum(p);
  __syncthreads();
  if (lane==0) red[w] = p;
  __syncthreads();
  if (tid==0) atomicAdd(&outp[g], red[0]+red[1]+red[2]+red[3]);
}

extern "C" void kernel_launch(void* const* d_in, const int* in_sizes, int n_in,
                              void* d_out, int out_size, void* d_ws, size_t ws_size,
                              hipStream_t stream) {
  const float* solute_x  = (const float*)d_in[0];
  const float* solvent_x = (const float*)d_in[1];
  const int*   ub        = (const int*)d_in[2];
  const int*   vb        = (const int*)d_in[3];
  const float* Wih  = (const float*)d_in[5];
  const float* Whh  = (const float*)d_in[6];
  const float* b_ih = (const float*)d_in[7];
  const float* b_hh = (const float*)d_in[8];
  const float* pW   = (const float*)d_in[9];
  const float* pb   = (const float*)d_in[10];

  int Nu = in_sizes[0] / HDIM;
  int Nv = in_sizes[1] / HDIM;

  float* out = (float*)d_out;
  int predn = out_size - Nu*Nv;        // = 256
  float* mapbase = out + predn;

  float* ws = (float*)d_ws;
  float* su    = ws;
  float* sv    = su    + (size_t)Nu*HDIM;
  float* spr   = sv    + (size_t)Nv*HDIM;
  float* svp   = spr   + (size_t)Nu*HDIM;
  float* e1u   = svp   + (size_t)Nv*HDIM;  // Nu
  float* e1v   = e1u   + Nu;               // Nv
  float* h1    = e1v   + Nv;               // 600
  float* c1    = h1    + DDIM;             // 600
  float* r1    = c1    + DDIM;             // 512*600
  float* gbase = r1    + 512*DDIM;         // 2400
  float* h2    = gbase + 2400;             // 512*600
  int*   uoff  = (int*)(h2 + 512*DDIM);    // 257
  int*   voff  = uoff + 257;               // 257

  int NBn = (Nu + Nv) / 4;
  k_norm_fill_off<<<dim3(NBn + 1 + Nu), dim3(256), 0, stream>>>(
      solute_x, solvent_x, su, sv, Nu, Nv, ub, vb, uoff, voff,
      b_ih, b_hh, h1, c1, pb, out, mapbase);
  k_prime<<<dim3(Nu+Nv), dim3(256), 0, stream>>>(
      su, sv, ub, vb, uoff, voff, spr, svp, e1u, e1v, h1, mapbase, Nu, Nv);
  k_r1_gbase<<<dim3(512+600), dim3(256), 0, stream>>>(
      su, sv, spr, svp, e1u, e1v, uoff, voff, r1, h1, Wih, Whh, b_ih, b_hh, gbase);
  k_gemm_lstm<<<dim3(38, 16), dim3(256), 0, stream>>>(r1, Wih, gbase, c1, h2);
  k_r2<<<dim3(512), dim3(256), 0, stream>>>(
      su, sv, spr, svp, uoff, voff, h2, pW, e1u, e1v, out);
}

// Round 5
// 534.954 us; speedup vs baseline: 1.1046x; 1.0255x over previous
//
#include <hip/hip_runtime.h>
#include <math.h>

// Problem constants: H=300, D=600, B=256 graphs, Nu=Nv=8192, batch SORTED.
#define HDIM 300
#define DDIM 600
#define NGR  256

typedef float vf4 __attribute__((ext_vector_type(4)));
typedef float vf2 __attribute__((ext_vector_type(2)));

__device__ __forceinline__ float wred_sum(float v){
  #pragma unroll
  for(int o=32;o;o>>=1) v += __shfl_xor(v,o,64);
  return v;
}
__device__ __forceinline__ float wred_max(float v){
  #pragma unroll
  for(int o=32;o;o>>=1) v = fmaxf(v,__shfl_xor(v,o,64));
  return v;
}
__device__ __forceinline__ float sigm(float x){ return 1.f/(1.f+expf(-x)); }

// Zero-fill map row i outside its in-graph span [js,je) (NT float4 stores).
// Disjoint from the dot writes, so it can ride in ANY kernel's grid.
__device__ __forceinline__ void fill_row(int i, const int* __restrict__ ub,
    const int* __restrict__ voff, float* __restrict__ mapbase, int Nv, int tid){
  int g = ub[i];
  int js = voff[g], je = voff[g+1];
  float* mrow = mapbase + (size_t)i*Nv;
  const vf4 z4 = {0.f,0.f,0.f,0.f};
  int nf4 = Nv >> 2;
  for (int q4=tid; q4<nf4; q4+=256){
    int j0 = q4*4;
    if (j0+4 <= js || j0 >= je){
      __builtin_nontemporal_store(z4, (vf4*)(mrow + j0));
    } else {
      #pragma unroll
      for(int u=0;u<4;u++){ int j=j0+u; if (j<js || j>=je) mrow[j]=0.f; }
    }
  }
}

// ---- K1: l2-normalize rows (4 waves/block); last block: offsets (binary
// search), step-1 LSTM closed form (gates = b_ih+b_hh), out init. -----------
__global__ __launch_bounds__(256) void k_norm_off(const float* __restrict__ xu,
    const float* __restrict__ xv, float* __restrict__ su, float* __restrict__ sv,
    int Nu, int Nv, const int* __restrict__ ub, const int* __restrict__ vb,
    int* __restrict__ uoff, int* __restrict__ voff,
    const float* __restrict__ b_ih, const float* __restrict__ b_hh,
    float* __restrict__ h1, float* __restrict__ c1,
    const float* __restrict__ pb, float* __restrict__ outp){
  if (blockIdx.x == gridDim.x - 1){
    int t = threadIdx.x;
    if (t < NGR){
      int lo=0, hi=Nu;
      while(lo<hi){ int m=(lo+hi)>>1; if (ub[m] < t) lo=m+1; else hi=m; }
      uoff[t]=lo;
      lo=0; hi=Nv;
      while(lo<hi){ int m=(lo+hi)>>1; if (vb[m] < t) lo=m+1; else hi=m; }
      voff[t]=lo;
      if (t==0){ uoff[NGR]=Nu; voff[NGR]=Nv; }
      outp[t] = pb[0];
    }
    for (int d=threadIdx.x; d<DDIM; d+=256){
      float gi = b_ih[d]      + b_hh[d];
      float gg = b_ih[1200+d] + b_hh[1200+d];
      float go = b_ih[1800+d] + b_hh[1800+d];
      float c  = sigm(gi)*tanhf(gg);       // f*c0 = 0
      c1[d]=c; h1[d]=sigm(go)*tanhf(c);
    }
    return;
  }
  int wid = blockIdx.x*4 + (threadIdx.x >> 6);
  int lane = threadIdx.x & 63;
  const float* src; float* dst;
  if (wid < Nu){ src = xu + (size_t)wid*HDIM; dst = su + (size_t)wid*HDIM; }
  else         { src = xv + (size_t)(wid-Nu)*HDIM; dst = sv + (size_t)(wid-Nu)*HDIM; }
  const vf4* s4 = (const vf4*)src;
  vf4 A = s4[lane];
  vf4 Bv = (lane<11)? s4[64+lane] : (vf4){0.f,0.f,0.f,0.f};
  float s = A.x*A.x+A.y*A.y+A.z*A.z+A.w*A.w + Bv.x*Bv.x+Bv.y*Bv.y+Bv.z*Bv.z+Bv.w*Bv.w;
  s = wred_sum(s);
  float inv = 1.f / fmaxf(sqrtf(s), 1e-12f);
  vf4* d4 = (vf4*)dst;
  d4[lane] = A*inv;
  if (lane<11) d4[64+lane] = Bv*inv;
}

// ---- K2: blocks [0,Nu+Nv): per-row prime (solute rows write map dots);
// [Nu+Nv, +600): gbase; rest: map fill rows [0,4096). -----------------------
__global__ __launch_bounds__(256) void k_prime(const float* __restrict__ su,
    const float* __restrict__ sv, const int* __restrict__ ub,
    const int* __restrict__ vb, const int* __restrict__ uoff,
    const int* __restrict__ voff, float* __restrict__ spr,
    float* __restrict__ svp, float* __restrict__ e1u, float* __restrict__ e1v,
    const float* __restrict__ h1, float* __restrict__ mapbase, int Nu, int Nv,
    const float* __restrict__ Wih, const float* __restrict__ Whh,
    const float* __restrict__ b_ih, const float* __restrict__ b_hh,
    float* __restrict__ gbase){
  int b = blockIdx.x;
  int tid = threadIdx.x, lane = tid & 63, w = tid >> 6;
  if (b >= Nu + Nv){
    int e = b - (Nu + Nv);
    if (e < 600){                          // gbase: n = e*4 + w
      int n = e*4 + w;
      const float* wi = Wih + (size_t)n*1200;
      const float* wh = Whh + (size_t)n*600;
      float s = 0.f;
      for (int k=lane; k<DDIM; k+=64) s += h1[k]*(wi[k] + wh[k]);
      s = wred_sum(s);
      if (lane==0) gbase[n] = s + b_ih[n] + b_hh[n];
    } else {
      fill_row(e - 600, ub, voff, mapbase, Nv, tid);
    }
    return;
  }
  bool isU = (b < Nu);
  int i = isU ? b : b - Nu;
  const float* xa = isU ? su : sv;
  const float* xb = isU ? sv : su;
  const int* mybatch = isU ? ub : vb;
  const int* ooff    = isU ? voff : uoff;
  float* prime = isU ? spr : svp;
  float* eout  = isU ? e1u : e1v;

  __shared__ __align__(16) float xrow[304];
  __shared__ __align__(16) float prl[4*304];
  __shared__ float qv[2*HDIM];
  __shared__ float red[4];
  const float* rowp = xa + (size_t)i*HDIM;
  for (int t=tid; t<HDIM;   t+=256) xrow[t] = rowp[t];
  for (int t=tid; t<2*HDIM; t+=256) qv[t]   = h1[t];
  int g = mybatch[i];
  int js = ooff[g], je = ooff[g+1];
  __syncthreads();

  const vf4* x4 = (const vf4*)xrow;
  vf4 xA = x4[lane];
  vf4 xB = (lane<11)? x4[64+lane] : (vf4){0.f,0.f,0.f,0.f};
  vf4 prA = {0.f,0.f,0.f,0.f}, prB = {0.f,0.f,0.f,0.f};
  for (int j = js + w; j < je; j += 4){
    const vf4* orow = (const vf4*)(xb + (size_t)j*HDIM);
    vf4 oA = orow[lane];
    vf4 oB = (lane<11)? orow[64+lane] : (vf4){0.f,0.f,0.f,0.f};
    float d = oA.x*xA.x + oA.y*xA.y + oA.z*xA.z + oA.w*xA.w
            + oB.x*xB.x + oB.y*xB.y + oB.z*xB.z + oB.w*xB.w;
    d = wred_sum(d);
    if (isU && lane==0) mapbase[(size_t)i*Nv + j] = d;
    prA += d * oA;
    prB += d * oB;
  }
  vf4* p4 = (vf4*)(prl + w*304);
  p4[lane] = prA;
  if (lane<11) p4[64+lane] = prB;
  __syncthreads();
  float ep = 0.f;
  for (int t=tid; t<HDIM; t+=256){
    float s = prl[t] + prl[304+t] + prl[608+t] + prl[912+t];
    prime[(size_t)i*HDIM + t] = s;
    ep += xrow[t]*qv[t] + s*qv[HDIM+t];
  }
  ep = wred_sum(ep);
  if (lane==0) red[w] = ep;
  __syncthreads();
  if (tid==0) eout[i] = red[0]+red[1]+red[2]+red[3];
}

// ---- K3: blocks [0,512): segment softmax + r1; rest: fill rows [4096,6144) -
__global__ __launch_bounds__(256) void k_r1(const float* __restrict__ su,
    const float* __restrict__ sv, const float* __restrict__ spr,
    const float* __restrict__ svp, const float* __restrict__ e1u,
    const float* __restrict__ e1v, const int* __restrict__ uoff,
    const int* __restrict__ voff, float* __restrict__ r1,
    const int* __restrict__ ub, float* __restrict__ mapbase, int Nv){
  int tid = threadIdx.x, lane = tid & 63, w = tid >> 6;
  if (blockIdx.x >= 512){
    fill_row(4096 + (blockIdx.x - 512), ub, voff, mapbase, Nv, tid);
    return;
  }
  int bs = blockIdx.x; int set = bs >> 8; int g = bs & 255;
  const float* x  = set? sv  : su;
  const float* pr = set? svp : spr;
  const float* e  = set? e1v : e1u;
  const int* off  = set? voff: uoff;
  __shared__ float al[2048]; __shared__ float red[4]; __shared__ float shv;
  int ns = off[g], ne = off[g+1]; int n = ne - ns;
  float m = -INFINITY;
  for (int t=ns+tid; t<ne; t+=256) m = fmaxf(m, e[t]);
  m = wred_max(m);
  if (lane==0) red[w]=m;
  __syncthreads();
  if (tid==0) shv = fmaxf(fmaxf(red[0],red[1]),fmaxf(red[2],red[3]));
  __syncthreads();
  float emax = shv;
  float s = 0.f;
  for (int t=tid; t<n; t+=256){ float a = expf(e[ns+t]-emax); if (t<2048) al[t]=a; s += a; }
  s = wred_sum(s);
  __syncthreads();
  if (lane==0) red[w]=s;
  __syncthreads();
  if (tid==0) shv = red[0]+red[1]+red[2]+red[3];
  __syncthreads();
  float inv = 1.f/(shv + 1e-16f);
  float acc[3] = {0.f,0.f,0.f};
  for (int nn=0; nn<n; nn++){
    float a = (nn<2048)? al[nn] : expf(e[ns+nn]-emax);
    const float* xr = x  + (size_t)(ns+nn)*HDIM;
    const float* pp = pr + (size_t)(ns+nn)*HDIM;
    #pragma unroll
    for(int u=0;u<3;u++){ int c = tid + u*256; if (c<DDIM){
        float xv = (c<HDIM)? xr[c] : pp[c-HDIM]; acc[u] += a*xv; } }
  }
  #pragma unroll
  for(int u=0;u<3;u++){ int c = tid + u*256; if (c<DDIM) r1[(size_t)bs*DDIM + c] = acc[u]*inv; }
}

// ---- K4: fused GEMM (gates = r1 @ Wih[:,600:].T) + step-2 LSTM pointwise.
// 32 gs x 64 col tile (cols = 4 gates x 16 d), grid 38x16 = 608 blocks. -----
__global__ __launch_bounds__(256) void k_gemm_lstm(const float* __restrict__ r1,
    const float* __restrict__ Wih, const float* __restrict__ gbase,
    const float* __restrict__ c1, float* __restrict__ h2){
  __shared__ __align__(16) float smem[32*68];   // gates phase; K phase aliases
  float* Al = smem;            // 16*36
  float* Bl = smem + 16*36;    // 16*68
  int tid = threadIdx.x;
  int d0  = blockIdx.x*16;     // 38 blocks: d0 = 0..592 (last has 8 valid)
  int gs0 = blockIdx.y*32;
  int tx = tid & 15, ty = tid >> 4;
  float acc[2][4] = {};
  for (int kt=0; kt<600; kt+=16){
    int k = kt + tx;
    bool kok = (k < 600);
    #pragma unroll
    for (int u=0; u<2; u++){
      int rl = ty + u*16;
      Al[tx*36 + rl] = kok ? r1[(size_t)(gs0+rl)*DDIM + k] : 0.f;
    }
    #pragma unroll
    for (int u=0; u<4; u++){
      int cl = ty + u*16;                 // 0..63
      int gate = cl >> 4, dd = cl & 15;
      int d = d0 + dd;
      Bl[tx*68 + cl] = (kok && d < 600)
          ? Wih[(size_t)(gate*600 + d)*1200 + 600 + k] : 0.f;
    }
    __syncthreads();
    #pragma unroll
    for (int kk=0; kk<16; kk++){
      vf2 av = ((const vf2*)(Al + kk*36))[ty];
      vf4 bv = ((const vf4*)(Bl + kk*68))[tx];
      float a[2]={av.x,av.y}, bb[4]={bv.x,bv.y,bv.z,bv.w};
      #pragma unroll
      for(int mm=0;mm<2;mm++)
        #pragma unroll
        for(int nn=0;nn<4;nn++) acc[mm][nn] += a[mm]*bb[nn];
    }
    __syncthreads();
  }
  #pragma unroll
  for (int mm=0; mm<2; mm++){
    vf4 o = {acc[mm][0], acc[mm][1], acc[mm][2], acc[mm][3]};
    ((vf4*)(smem + (ty*2+mm)*68))[tx] = o;
  }
  __syncthreads();
  int d_l = tid & 15, r0 = tid >> 4;
  int d = d0 + d_l;
  if (d < 600){
    float gb_i = gbase[d], gb_f = gbase[600+d], gb_g = gbase[1200+d], gb_o = gbase[1800+d];
    float cc1 = c1[d];
    #pragma unroll
    for (int u=0; u<2; u++){
      int rl = r0 + u*16;
      const float* gr = smem + rl*68;
      float gi = gr[d_l]      + gb_i;
      float gf = gr[16+d_l]   + gb_f;
      float gG = gr[32+d_l]   + gb_g;
      float go = gr[48+d_l]   + gb_o;
      float c  = sigm(gf)*cc1 + sigm(gi)*tanhf(gG);
      h2[(size_t)(gs0+rl)*DDIM + d] = sigm(go)*tanhf(c);
    }
  }
}

// ---- K5: blocks [0,512): e2/softmax/r2 + atomicAdd prediction;
// rest: fill rows [6144,8192). ----------------------------------------------
__global__ __launch_bounds__(256) void k_r2(const float* __restrict__ su,
    const float* __restrict__ sv, const float* __restrict__ spr,
    const float* __restrict__ svp, const int* __restrict__ uoff,
    const int* __restrict__ voff, const float* __restrict__ h2,
    const float* __restrict__ pW, float* __restrict__ e2u,
    float* __restrict__ e2v, float* __restrict__ outp,
    const int* __restrict__ ub, float* __restrict__ mapbase, int Nv){
  int tid = threadIdx.x, lane = tid & 63, w = tid >> 6;
  if (blockIdx.x >= 512){
    fill_row(6144 + (blockIdx.x - 512), ub, voff, mapbase, Nv, tid);
    return;
  }
  int bs = blockIdx.x; int set = bs >> 8; int g = bs & 255;
  const float* x  = set? sv  : su;
  const float* pr = set? svp : spr;
  const int* off  = set? voff: uoff;
  float* e2       = set? e2v : e2u;
  __shared__ float q[DDIM]; __shared__ float al[2048];
  __shared__ float red[4]; __shared__ float shv;
  for (int t=tid; t<DDIM; t+=256) q[t] = h2[(size_t)bs*DDIM + t];
  int ns = off[g], ne = off[g+1]; int n = ne - ns;
  __syncthreads();
  for (int node = ns + w; node < ne; node += 4){
    const float* xr = x  + (size_t)node*HDIM;
    const float* pp = pr + (size_t)node*HDIM;
    float d = 0.f;
    #pragma unroll
    for(int c=0;c<10;c++){ int k = lane + 64*c; if (k<DDIM){
        float xv = (k<HDIM)? xr[k] : pp[k-HDIM]; d += xv*q[k]; } }
    d = wred_sum(d);
    if (lane==0) e2[node] = d;
  }
  __syncthreads();
  float m = -INFINITY;
  for (int t=ns+tid; t<ne; t+=256) m = fmaxf(m, e2[t]);
  m = wred_max(m);
  if (lane==0) red[w]=m;
  __syncthreads();
  if (tid==0) shv = fmaxf(fmaxf(red[0],red[1]),fmaxf(red[2],red[3]));
  __syncthreads();
  float emax = shv;
  float s = 0.f;
  for (int t=tid; t<n; t+=256){ float a = expf(e2[ns+t]-emax); if (t<2048) al[t]=a; s += a; }
  s = wred_sum(s);
  __syncthreads();
  if (lane==0) red[w]=s;
  __syncthreads();
  if (tid==0) shv = red[0]+red[1]+red[2]+red[3];
  __syncthreads();
  float inv = 1.f/(shv + 1e-16f);
  float acc[3] = {0.f,0.f,0.f};
  for (int nn=0; nn<n; nn++){
    float a = (nn<2048)? al[nn] : expf(e2[ns+nn]-emax);
    const float* xr = x  + (size_t)(ns+nn)*HDIM;
    const float* pp = pr + (size_t)(ns+nn)*HDIM;
    #pragma unroll
    for(int u=0;u<3;u++){ int c = tid + u*256; if (c<DDIM){
        float xv = (c<HDIM)? xr[c] : pp[c-HDIM]; acc[u] += a*xv; } }
  }
  int hoff = set? 1200 : 0;
  float p = 0.f;
  #pragma unroll
  for(int u=0;u<3;u++){ int c = tid + u*256; if (c<DDIM) p += (acc[u]*inv)*pW[hoff+600+c]; }
  for (int t=tid; t<DDIM; t+=256) p += q[t]*pW[hoff+t];
  p = wred_sum(p);
  __syncthreads();
  if (lane==0) red[w] = p;
  __syncthreads();
  if (tid==0) atomicAdd(&outp[g], red[0]+red[1]+red[2]+red[3]);
}

extern "C" void kernel_launch(void* const* d_in, const int* in_sizes, int n_in,
                              void* d_out, int out_size, void* d_ws, size_t ws_size,
                              hipStream_t stream) {
  const float* solute_x  = (const float*)d_in[0];
  const float* solvent_x = (const float*)d_in[1];
  const int*   ub        = (const int*)d_in[2];
  const int*   vb        = (const int*)d_in[3];
  const float* Wih  = (const float*)d_in[5];
  const float* Whh  = (const float*)d_in[6];
  const float* b_ih = (const float*)d_in[7];
  const float* b_hh = (const float*)d_in[8];
  const float* pW   = (const float*)d_in[9];
  const float* pb   = (const float*)d_in[10];

  int Nu = in_sizes[0] / HDIM;
  int Nv = in_sizes[1] / HDIM;

  float* out = (float*)d_out;
  int predn = out_size - Nu*Nv;        // = 256
  float* mapbase = out + predn;

  float* ws = (float*)d_ws;
  float* su    = ws;
  float* sv    = su    + (size_t)Nu*HDIM;
  float* spr   = sv    + (size_t)Nv*HDIM;
  float* svp   = spr   + (size_t)Nu*HDIM;
  float* e1u   = svp   + (size_t)Nv*HDIM;  // Nu
  float* e1v   = e1u   + Nu;               // Nv
  float* h1    = e1v   + Nv;               // 600
  float* c1    = h1    + DDIM;             // 600
  float* r1    = c1    + DDIM;             // 512*600
  float* gbase = r1    + 512*DDIM;         // 2400
  float* h2    = gbase + 2400;             // 512*600
  int*   uoff  = (int*)(h2 + 512*DDIM);    // 257
  int*   voff  = uoff + 257;               // 257

  // Fill split: K2 gets rows [0,4096), K3 [4096,6144), K5 [6144,8192).
  k_norm_off<<<dim3((Nu+Nv)/4 + 1), dim3(256), 0, stream>>>(
      solute_x, solvent_x, su, sv, Nu, Nv, ub, vb, uoff, voff,
      b_ih, b_hh, h1, c1, pb, out);
  k_prime<<<dim3(Nu+Nv + 600 + 4096), dim3(256), 0, stream>>>(
      su, sv, ub, vb, uoff, voff, spr, svp, e1u, e1v, h1, mapbase, Nu, Nv,
      Wih, Whh, b_ih, b_hh, gbase);
  k_r1<<<dim3(512 + 2048), dim3(256), 0, stream>>>(
      su, sv, spr, svp, e1u, e1v, uoff, voff, r1, ub, mapbase, Nv);
  k_gemm_lstm<<<dim3(38, 16), dim3(256), 0, stream>>>(r1, Wih, gbase, c1, h2);
  k_r2<<<dim3(512 + 2048), dim3(256), 0, stream>>>(
      su, sv, spr, svp, uoff, voff, h2, pW, e1u, e1v, out, ub, mapbase, Nv);
}

// Round 6
// 524.553 us; speedup vs baseline: 1.1265x; 1.0198x over previous
//
#include <hip/hip_runtime.h>
#include <math.h>

// Problem constants: H=300, D=600, B=256 graphs, Nu=Nv=8192, batch SORTED.
#define HDIM 300
#define DDIM 600
#define NGR  256

typedef float vf4 __attribute__((ext_vector_type(4)));
typedef float vf2 __attribute__((ext_vector_type(2)));

__device__ __forceinline__ float wred_sum(float v){
  #pragma unroll
  for(int o=32;o;o>>=1) v += __shfl_xor(v,o,64);
  return v;
}
__device__ __forceinline__ float wred_max(float v){
  #pragma unroll
  for(int o=32;o;o>>=1) v = fmaxf(v,__shfl_xor(v,o,64));
  return v;
}
__device__ __forceinline__ float sigm(float x){ return 1.f/(1.f+expf(-x)); }

// Zero-fill map row i outside its in-graph span [js,je) (NT float4 stores).
// Disjoint from the dot writes, so order vs compute is free.
__device__ __forceinline__ void fill_row(int i, const int* __restrict__ ub,
    const int* __restrict__ voff, float* __restrict__ mapbase, int Nv, int tid){
  int g = ub[i];
  int js = voff[g], je = voff[g+1];
  float* mrow = mapbase + (size_t)i*Nv;
  const vf4 z4 = {0.f,0.f,0.f,0.f};
  int nf4 = Nv >> 2;
  for (int q4=tid; q4<nf4; q4+=256){
    int j0 = q4*4;
    if (j0+4 <= js || j0 >= je){
      __builtin_nontemporal_store(z4, (vf4*)(mrow + j0));
    } else {
      #pragma unroll
      for(int u=0;u<4;u++){ int j=j0+u; if (j<js || j>=je) mrow[j]=0.f; }
    }
  }
}

// ---- K1: blocks [0,NBn): l2-normalize rows (4 waves/block);
//  NBn: offsets (binary search) + step-1 LSTM closed form + out init;
//  (NBn, NBn+600]: gbase (recomputes bias-only h1 locally -> no cross-block dep).
__global__ __launch_bounds__(256) void k_norm_off(const float* __restrict__ xu,
    const float* __restrict__ xv, float* __restrict__ su, float* __restrict__ sv,
    int Nu, int Nv, const int* __restrict__ ub, const int* __restrict__ vb,
    int* __restrict__ uoff, int* __restrict__ voff,
    const float* __restrict__ b_ih, const float* __restrict__ b_hh,
    float* __restrict__ h1, float* __restrict__ c1,
    const float* __restrict__ pb, float* __restrict__ outp,
    const float* __restrict__ Wih, const float* __restrict__ Whh,
    float* __restrict__ gbase){
  int NBn = (Nu + Nv) >> 2;
  int b = blockIdx.x;
  int tid = threadIdx.x, lane = tid & 63, w = tid >> 6;
  if (b == NBn){
    int t = tid;
    if (t < NGR){
      int lo=0, hi=Nu;
      while(lo<hi){ int m=(lo+hi)>>1; if (ub[m] < t) lo=m+1; else hi=m; }
      uoff[t]=lo;
      lo=0; hi=Nv;
      while(lo<hi){ int m=(lo+hi)>>1; if (vb[m] < t) lo=m+1; else hi=m; }
      voff[t]=lo;
      if (t==0){ uoff[NGR]=Nu; voff[NGR]=Nv; }
      outp[t] = pb[0];
    }
    for (int d=tid; d<DDIM; d+=256){
      float gi = b_ih[d]      + b_hh[d];
      float gg = b_ih[1200+d] + b_hh[1200+d];
      float go = b_ih[1800+d] + b_hh[1800+d];
      float c  = sigm(gi)*tanhf(gg);       // f*c0 = 0
      c1[d]=c; h1[d]=sigm(go)*tanhf(c);
    }
    return;
  }
  if (b > NBn){                            // gbase blocks
    __shared__ float h1l[DDIM];
    for (int d=tid; d<DDIM; d+=256){       // recompute bias-only h1 locally
      float gi = b_ih[d]      + b_hh[d];
      float gg = b_ih[1200+d] + b_hh[1200+d];
      float go = b_ih[1800+d] + b_hh[1800+d];
      float c  = sigm(gi)*tanhf(gg);
      h1l[d]   = sigm(go)*tanhf(c);
    }
    __syncthreads();
    int n = (b - NBn - 1)*4 + w;           // 600 blocks x 4 waves = 2400 rows
    const float* wi = Wih + (size_t)n*1200;
    const float* wh = Whh + (size_t)n*600;
    float s = 0.f;
    for (int k=lane; k<DDIM; k+=64) s += h1l[k]*(wi[k] + wh[k]);
    s = wred_sum(s);
    if (lane==0) gbase[n] = s + b_ih[n] + b_hh[n];
    return;
  }
  int wid = b*4 + w;
  const float* src; float* dst;
  if (wid < Nu){ src = xu + (size_t)wid*HDIM; dst = su + (size_t)wid*HDIM; }
  else         { src = xv + (size_t)(wid-Nu)*HDIM; dst = sv + (size_t)(wid-Nu)*HDIM; }
  const vf4* s4 = (const vf4*)src;
  vf4 A = s4[lane];
  vf4 Bv = (lane<11)? s4[64+lane] : (vf4){0.f,0.f,0.f,0.f};
  float s = A.x*A.x+A.y*A.y+A.z*A.z+A.w*A.w + Bv.x*Bv.x+Bv.y*Bv.y+Bv.z*Bv.z+Bv.w*Bv.w;
  s = wred_sum(s);
  float inv = 1.f / fmaxf(sqrtf(s), 1e-12f);
  vf4* d4 = (vf4*)dst;
  d4[lane] = A*inv;
  if (lane<11) d4[64+lane] = Bv*inv;
}

// ---- K2: grid 24576 = 16384 compute + 8192 fill, INTERLEAVED (b%3==2 ->
// fill row b/3) so store-bound fill overlaps latency-bound compute on every CU.
__global__ __launch_bounds__(256) void k_prime(const float* __restrict__ su,
    const float* __restrict__ sv, const int* __restrict__ ub,
    const int* __restrict__ vb, const int* __restrict__ uoff,
    const int* __restrict__ voff, float* __restrict__ spr,
    float* __restrict__ svp, float* __restrict__ e1u, float* __restrict__ e1v,
    const float* __restrict__ h1, float* __restrict__ mapbase, int Nu, int Nv){
  int b = blockIdx.x;
  int tid = threadIdx.x, lane = tid & 63, w = tid >> 6;
  int r = b % 3;
  if (r == 2){ fill_row(b/3, ub, voff, mapbase, Nv, tid); return; }
  int idx = (b/3)*2 + r;                   // [0, 16384)
  bool isU = (idx < Nu);
  int i = isU ? idx : idx - Nu;
  const float* xa = isU ? su : sv;
  const float* xb = isU ? sv : su;
  const int* mybatch = isU ? ub : vb;
  const int* ooff    = isU ? voff : uoff;
  float* prime = isU ? spr : svp;
  float* eout  = isU ? e1u : e1v;

  __shared__ __align__(16) float xrow[304];
  __shared__ __align__(16) float prl[4*304];
  __shared__ float qv[2*HDIM];
  __shared__ float red[4];
  const float* rowp = xa + (size_t)i*HDIM;
  for (int t=tid; t<HDIM;   t+=256) xrow[t] = rowp[t];
  for (int t=tid; t<2*HDIM; t+=256) qv[t]   = h1[t];
  int g = mybatch[i];
  int js = ooff[g], je = ooff[g+1];
  __syncthreads();

  const vf4* x4 = (const vf4*)xrow;
  vf4 xA = x4[lane];
  vf4 xB = (lane<11)? x4[64+lane] : (vf4){0.f,0.f,0.f,0.f};
  vf4 prA = {0.f,0.f,0.f,0.f}, prB = {0.f,0.f,0.f,0.f};
  for (int j = js + w; j < je; j += 4){
    const vf4* orow = (const vf4*)(xb + (size_t)j*HDIM);
    vf4 oA = orow[lane];
    vf4 oB = (lane<11)? orow[64+lane] : (vf4){0.f,0.f,0.f,0.f};
    float d = oA.x*xA.x + oA.y*xA.y + oA.z*xA.z + oA.w*xA.w
            + oB.x*xB.x + oB.y*xB.y + oB.z*xB.z + oB.w*xB.w;
    d = wred_sum(d);
    if (isU && lane==0) mapbase[(size_t)i*Nv + j] = d;
    prA += d * oA;
    prB += d * oB;
  }
  vf4* p4 = (vf4*)(prl + w*304);
  p4[lane] = prA;
  if (lane<11) p4[64+lane] = prB;
  __syncthreads();
  float ep = 0.f;
  for (int t=tid; t<HDIM; t+=256){
    float s = prl[t] + prl[304+t] + prl[608+t] + prl[912+t];
    prime[(size_t)i*HDIM + t] = s;
    ep += xrow[t]*qv[t] + s*qv[HDIM+t];
  }
  ep = wred_sum(ep);
  if (lane==0) red[w] = ep;
  __syncthreads();
  if (tid==0) eout[i] = red[0]+red[1]+red[2]+red[3];
}

// ---- K3: 512 blocks: segment softmax over e1 + r1 -------------------------
__global__ __launch_bounds__(256) void k_r1(const float* __restrict__ su,
    const float* __restrict__ sv, const float* __restrict__ spr,
    const float* __restrict__ svp, const float* __restrict__ e1u,
    const float* __restrict__ e1v, const int* __restrict__ uoff,
    const int* __restrict__ voff, float* __restrict__ r1){
  int tid = threadIdx.x, lane = tid & 63, w = tid >> 6;
  int bs = blockIdx.x; int set = bs >> 8; int g = bs & 255;
  const float* x  = set? sv  : su;
  const float* pr = set? svp : spr;
  const float* e  = set? e1v : e1u;
  const int* off  = set? voff: uoff;
  __shared__ float al[2048]; __shared__ float red[4]; __shared__ float shv;
  int ns = off[g], ne = off[g+1]; int n = ne - ns;
  float m = -INFINITY;
  for (int t=ns+tid; t<ne; t+=256) m = fmaxf(m, e[t]);
  m = wred_max(m);
  if (lane==0) red[w]=m;
  __syncthreads();
  if (tid==0) shv = fmaxf(fmaxf(red[0],red[1]),fmaxf(red[2],red[3]));
  __syncthreads();
  float emax = shv;
  float s = 0.f;
  for (int t=tid; t<n; t+=256){ float a = expf(e[ns+t]-emax); if (t<2048) al[t]=a; s += a; }
  s = wred_sum(s);
  __syncthreads();
  if (lane==0) red[w]=s;
  __syncthreads();
  if (tid==0) shv = red[0]+red[1]+red[2]+red[3];
  __syncthreads();
  float inv = 1.f/(shv + 1e-16f);
  float acc[3] = {0.f,0.f,0.f};
  for (int nn=0; nn<n; nn++){
    float a = (nn<2048)? al[nn] : expf(e[ns+nn]-emax);
    const float* xr = x  + (size_t)(ns+nn)*HDIM;
    const float* pp = pr + (size_t)(ns+nn)*HDIM;
    #pragma unroll
    for(int u=0;u<3;u++){ int c = tid + u*256; if (c<DDIM){
        float xv = (c<HDIM)? xr[c] : pp[c-HDIM]; acc[u] += a*xv; } }
  }
  #pragma unroll
  for(int u=0;u<3;u++){ int c = tid + u*256; if (c<DDIM) r1[(size_t)bs*DDIM + c] = acc[u]*inv; }
}

// ---- K4: fused GEMM (gates = r1 @ Wih[:,600:].T) + step-2 LSTM pointwise.
// 32 gs x 64 col tile (cols = 4 gates x 16 d), grid 38x16 = 608 blocks. -----
__global__ __launch_bounds__(256) void k_gemm_lstm(const float* __restrict__ r1,
    const float* __restrict__ Wih, const float* __restrict__ gbase,
    const float* __restrict__ c1, float* __restrict__ h2){
  __shared__ __align__(16) float smem[32*68];   // gates phase; K phase aliases
  float* Al = smem;            // 16*36
  float* Bl = smem + 16*36;    // 16*68
  int tid = threadIdx.x;
  int d0  = blockIdx.x*16;     // 38 blocks: d0 = 0..592 (last has 8 valid)
  int gs0 = blockIdx.y*32;
  int tx = tid & 15, ty = tid >> 4;
  float acc[2][4] = {};
  for (int kt=0; kt<600; kt+=16){
    int k = kt + tx;
    bool kok = (k < 600);
    #pragma unroll
    for (int u=0; u<2; u++){
      int rl = ty + u*16;
      Al[tx*36 + rl] = kok ? r1[(size_t)(gs0+rl)*DDIM + k] : 0.f;
    }
    #pragma unroll
    for (int u=0; u<4; u++){
      int cl = ty + u*16;                 // 0..63
      int gate = cl >> 4, dd = cl & 15;
      int d = d0 + dd;
      Bl[tx*68 + cl] = (kok && d < 600)
          ? Wih[(size_t)(gate*600 + d)*1200 + 600 + k] : 0.f;
    }
    __syncthreads();
    #pragma unroll
    for (int kk=0; kk<16; kk++){
      vf2 av = ((const vf2*)(Al + kk*36))[ty];
      vf4 bv = ((const vf4*)(Bl + kk*68))[tx];
      float a[2]={av.x,av.y}, bb[4]={bv.x,bv.y,bv.z,bv.w};
      #pragma unroll
      for(int mm=0;mm<2;mm++)
        #pragma unroll
        for(int nn=0;nn<4;nn++) acc[mm][nn] += a[mm]*bb[nn];
    }
    __syncthreads();
  }
  #pragma unroll
  for (int mm=0; mm<2; mm++){
    vf4 o = {acc[mm][0], acc[mm][1], acc[mm][2], acc[mm][3]};
    ((vf4*)(smem + (ty*2+mm)*68))[tx] = o;
  }
  __syncthreads();
  int d_l = tid & 15, r0 = tid >> 4;
  int d = d0 + d_l;
  if (d < 600){
    float gb_i = gbase[d], gb_f = gbase[600+d], gb_g = gbase[1200+d], gb_o = gbase[1800+d];
    float cc1 = c1[d];
    #pragma unroll
    for (int u=0; u<2; u++){
      int rl = r0 + u*16;
      const float* gr = smem + rl*68;
      float gi = gr[d_l]      + gb_i;
      float gf = gr[16+d_l]   + gb_f;
      float gG = gr[32+d_l]   + gb_g;
      float go = gr[48+d_l]   + gb_o;
      float c  = sigm(gf)*cc1 + sigm(gi)*tanhf(gG);
      h2[(size_t)(gs0+rl)*DDIM + d] = sigm(go)*tanhf(c);
    }
  }
}

// ---- K5: 512 blocks: e2 (in LDS) -> segment softmax -> r2 -> atomicAdd pred
__global__ __launch_bounds__(256) void k_r2(const float* __restrict__ su,
    const float* __restrict__ sv, const float* __restrict__ spr,
    const float* __restrict__ svp, const int* __restrict__ uoff,
    const int* __restrict__ voff, const float* __restrict__ h2,
    const float* __restrict__ pW, float* __restrict__ e2u,
    float* __restrict__ e2v, float* __restrict__ outp){
  int tid = threadIdx.x, lane = tid & 63, w = tid >> 6;
  int bs = blockIdx.x; int set = bs >> 8; int g = bs & 255;
  const float* x  = set? sv  : su;
  const float* pr = set? svp : spr;
  const int* off  = set? voff: uoff;
  float* e2g      = set? e2v : e2u;        // overflow fallback only
  __shared__ float q[DDIM]; __shared__ float e2l[128]; __shared__ float al[128];
  __shared__ float red[4]; __shared__ float shv;
  for (int t=tid; t<DDIM; t+=256) q[t] = h2[(size_t)bs*DDIM + t];
  int ns = off[g], ne = off[g+1]; int n = ne - ns;
  __syncthreads();
  for (int node = ns + w; node < ne; node += 4){
    const float* xr = x  + (size_t)node*HDIM;
    const float* pp = pr + (size_t)node*HDIM;
    float d = 0.f;
    #pragma unroll
    for(int c=0;c<10;c++){ int k = lane + 64*c; if (k<DDIM){
        float xv = (k<HDIM)? xr[k] : pp[k-HDIM]; d += xv*q[k]; } }
    d = wred_sum(d);
    if (lane==0){ int t = node-ns; if (t<128) e2l[t] = d; else e2g[node] = d; }
  }
  __syncthreads();
  float m = -INFINITY;
  for (int t=tid; t<n; t+=256) m = fmaxf(m, (t<128)? e2l[t] : e2g[ns+t]);
  m = wred_max(m);
  if (lane==0) red[w]=m;
  __syncthreads();
  if (tid==0) shv = fmaxf(fmaxf(red[0],red[1]),fmaxf(red[2],red[3]));
  __syncthreads();
  float emax = shv;
  float s = 0.f;
  for (int t=tid; t<n; t+=256){
    float a = expf(((t<128)? e2l[t] : e2g[ns+t]) - emax);
    if (t<128) al[t]=a; else e2g[ns+t]=a;
    s += a;
  }
  s = wred_sum(s);
  __syncthreads();
  if (lane==0) red[w]=s;
  __syncthreads();
  if (tid==0) shv = red[0]+red[1]+red[2]+red[3];
  __syncthreads();
  float inv = 1.f/(shv + 1e-16f);
  float acc[3] = {0.f,0.f,0.f};
  for (int nn=0; nn<n; nn++){
    float a = (nn<128)? al[nn] : e2g[ns+nn];
    const float* xr = x  + (size_t)(ns+nn)*HDIM;
    const float* pp = pr + (size_t)(ns+nn)*HDIM;
    #pragma unroll
    for(int u=0;u<3;u++){ int c = tid + u*256; if (c<DDIM){
        float xv = (c<HDIM)? xr[c] : pp[c-HDIM]; acc[u] += a*xv; } }
  }
  int hoff = set? 1200 : 0;
  float p = 0.f;
  #pragma unroll
  for(int u=0;u<3;u++){ int c = tid + u*256; if (c<DDIM) p += (acc[u]*inv)*pW[hoff+600+c]; }
  for (int t=tid; t<DDIM; t+=256) p += q[t]*pW[hoff+t];
  p = wred_sum(p);
  __syncthreads();
  if (lane==0) red[w] = p;
  __syncthreads();
  if (tid==0) atomicAdd(&outp[g], red[0]+red[1]+red[2]+red[3]);
}

extern "C" void kernel_launch(void* const* d_in, const int* in_sizes, int n_in,
                              void* d_out, int out_size, void* d_ws, size_t ws_size,
                              hipStream_t stream) {
  const float* solute_x  = (const float*)d_in[0];
  const float* solvent_x = (const float*)d_in[1];
  const int*   ub        = (const int*)d_in[2];
  const int*   vb        = (const int*)d_in[3];
  const float* Wih  = (const float*)d_in[5];
  const float* Whh  = (const float*)d_in[6];
  const float* b_ih = (const float*)d_in[7];
  const float* b_hh = (const float*)d_in[8];
  const float* pW   = (const float*)d_in[9];
  const float* pb   = (const float*)d_in[10];

  int Nu = in_sizes[0] / HDIM;
  int Nv = in_sizes[1] / HDIM;

  float* out = (float*)d_out;
  int predn = out_size - Nu*Nv;        // = 256
  float* mapbase = out + predn;

  float* ws = (float*)d_ws;
  float* su    = ws;
  float* sv    = su    + (size_t)Nu*HDIM;
  float* spr   = sv    + (size_t)Nv*HDIM;
  float* svp   = spr   + (size_t)Nu*HDIM;
  float* e1u   = svp   + (size_t)Nv*HDIM;  // Nu
  float* e1v   = e1u   + Nu;               // Nv
  float* h1    = e1v   + Nv;               // 600
  float* c1    = h1    + DDIM;             // 600
  float* r1    = c1    + DDIM;             // 512*600
  float* gbase = r1    + 512*DDIM;         // 2400
  float* h2    = gbase + 2400;             // 512*600
  int*   uoff  = (int*)(h2 + 512*DDIM);    // 257
  int*   voff  = uoff + 257;               // 257

  k_norm_off<<<dim3((Nu+Nv)/4 + 1 + 600), dim3(256), 0, stream>>>(
      solute_x, solvent_x, su, sv, Nu, Nv, ub, vb, uoff, voff,
      b_ih, b_hh, h1, c1, pb, out, Wih, Whh, gbase);
  k_prime<<<dim3(24576), dim3(256), 0, stream>>>(
      su, sv, ub, vb, uoff, voff, spr, svp, e1u, e1v, h1, mapbase, Nu, Nv);
  k_r1<<<dim3(512), dim3(256), 0, stream>>>(
      su, sv, spr, svp, e1u, e1v, uoff, voff, r1);
  k_gemm_lstm<<<dim3(38, 16), dim3(256), 0, stream>>>(r1, Wih, gbase, c1, h2);
  k_r2<<<dim3(512), dim3(256), 0, stream>>>(
      su, sv, spr, svp, uoff, voff, h2, pW, e1u, e1v, out);
}